// Round 24
// baseline (711.144 us; speedup 1.0000x reference)
//
#include <hip/hip_runtime.h>
#include <math.h>

#define B_    8
#define N_    5000
#define F_    15
#define NCIN  12
#define NCOUT 8
#define NMOM  3
#define H_    256
#define BINSZ 500
#define NBINS 10
#define KNN   16
#define ENCD  26   // NCIN + (F-1)
#define XRD   34   // ENCD + NCOUT
#define M_TOT (B_*N_)  // 40000

typedef unsigned short u16;
typedef _Float16 half8 __attribute__((ext_vector_type(8)));
typedef float f32x4_ __attribute__((ext_vector_type(4)));

__device__ __forceinline__ float elu_f(float x){ return x > 0.f ? x : expm1f(x); }
__device__ __forceinline__ float selu_f(float x){
    const float scale = 1.0507009873554804934193349852946f;
    const float alpha = 1.6732632423543772848170429916717f;
    return x > 0.f ? scale*x : scale*alpha*expm1f(x);
}
__device__ __forceinline__ float sigmoid_f(float x){ return 1.f/(1.f+expf(-x)); }
__device__ __forceinline__ u16 f2h(float x){ _Float16 h = (_Float16)x; return __builtin_bit_cast(u16, h); }
__device__ __forceinline__ float h2f(u16 u){ return (float)__builtin_bit_cast(_Float16, u); }

// ---------------------------------------------------------------- encode (fp32 + f16 hi/lo)
__global__ void k_encode(const float* __restrict__ X, float* __restrict__ enc,
                         u16* __restrict__ enc_h, u16* __restrict__ enc_l){
    int i = blockIdx.x*blockDim.x + threadIdx.x;
    if (i >= M_TOT) return;
    const float* x = X + (size_t)i*F_;
    float* e = enc + (size_t)i*ENCD;
    u16* eh = enc_h + (size_t)i*32;
    u16* el = enc_l + (size_t)i*32;
    int id = (int)x[0];
    #pragma unroll
    for (int c = 0; c < NCIN; ++c){
        float v = (c == id) ? 1.f : 0.f;
        e[c] = v; eh[c] = f2h(v); el[c] = 0;
    }
    #pragma unroll
    for (int f = 1; f < F_; ++f){
        float v = x[f];
        e[NCIN+f-1] = v;
        u16 h = f2h(v);
        eh[NCIN+f-1] = h;
        el[NCIN+f-1] = f2h(v - h2f(h));
    }
    #pragma unroll
    for (int c = ENCD; c < 32; ++c){ eh[c] = 0; el[c] = 0; }
}

// ---------------------------------------------------------------- weight prep (transpose + f16 / f16-lo)
#define NPREP 14
struct PrepArgs {
    const float* src[NPREP];
    u16* dst[NPREP];
    int K[NPREP];
    int Ka[NPREP];
    int lo[NPREP];
    int blk_end[NPREP];
};
__global__ void k_prep(PrepArgs a){
    int blk = blockIdx.x;
    int s = 0;
    while (blk >= a.blk_end[s]) s++;
    int base = s ? a.blk_end[s-1] : 0;
    int idx = (blk - base)*256 + threadIdx.x;
    int Ka = a.Ka[s];
    int n = idx / Ka, k = idx % Ka;
    float v = (k < a.K[s]) ? a.src[s][(size_t)k*H_ + n] : 0.f;
    u16 h = f2h(v);
    a.dst[s][idx] = a.lo[s] ? f2h(v - h2f(h)) : h;
}

// R [256][100] -> Rt [5][256]
__global__ void k_prepR(const float* __restrict__ R, float* __restrict__ Rt){
    int idx = blockIdx.x*256 + threadIdx.x;   // 5 blocks
    int j = idx >> 8, k = idx & 255;
    Rt[j*H_ + k] = R[(size_t)k*100 + j];
}

// ---------------------------------------------------------------- split-f16 MFMA GEMM for ffn chain
template<int ACT, int OUT>
__global__ __launch_bounds__(256) void k_ffn(const u16* __restrict__ Ahg,
        const u16* __restrict__ Alg, const u16* __restrict__ Whg,
        const u16* __restrict__ Wlg, const float* __restrict__ bias,
        float* __restrict__ Cf, u16* __restrict__ Ch, u16* __restrict__ Cl,
        int M, int K, int Nw){
    __shared__ u16 smem[12288];
    #define AH_(ks,m) (smem +        ((ks)*512  + (m)*8))
    #define AL_(ks,m) (smem + 2048 + ((ks)*512  + (m)*8))
    #define WH_(ks,m) (smem + 4096 + ((ks)*1024 + (m)*8))
    #define WL_(ks,m) (smem + 8192 + ((ks)*1024 + (m)*8))
    int tid = threadIdx.x, lane = tid & 63, w = tid >> 6;
    int wr = (w & 1)*32, wc = (w >> 1)*64;
    int m0 = blockIdx.x*64, n0 = blockIdx.y*128;
    int arow = tid >> 2, aks = tid & 3;
    const u16* ArH = Ahg + (size_t)(m0+arow)*K + aks*8;
    const u16* ArL = Alg + (size_t)(m0+arow)*K + aks*8;
    int wrow0 = tid >> 2, wks0 = tid & 3;
    int wrow1 = (tid + 256) >> 2, wks1 = tid & 3;
    const u16* WrH0 = Whg + (size_t)(n0+wrow0)*K + wks0*8;
    const u16* WrL0 = Wlg + (size_t)(n0+wrow0)*K + wks0*8;
    const u16* WrH1 = Whg + (size_t)(n0+wrow1)*K + wks1*8;
    const u16* WrL1 = Wlg + (size_t)(n0+wrow1)*K + wks1*8;
    f32x4_ z = {0.f,0.f,0.f,0.f};
    f32x4_ acc[2][4];
    #pragma unroll
    for (int i = 0; i < 2; ++i)
        #pragma unroll
        for (int j = 0; j < 4; ++j) acc[i][j] = z;
    const int fr = lane & 15, fks = lane >> 4;
    const int nc = K >> 5;
    uint4 rah, ral, rwh0, rwl0, rwh1, rwl1;

    rah  = *(const uint4*)(ArH);
    ral  = *(const uint4*)(ArL);
    rwh0 = *(const uint4*)(WrH0);
    rwl0 = *(const uint4*)(WrL0);
    rwh1 = *(const uint4*)(WrH1);
    rwl1 = *(const uint4*)(WrL1);
    *(uint4*)AH_(aks,arow) = rah;
    *(uint4*)AL_(aks,arow) = ral;
    *(uint4*)WH_(wks0,wrow0) = rwh0;
    *(uint4*)WL_(wks0,wrow0) = rwl0;
    *(uint4*)WH_(wks1,wrow1) = rwh1;
    *(uint4*)WL_(wks1,wrow1) = rwl1;
    __syncthreads();

    for (int c = 0; c < nc; ++c){
        if (c + 1 < nc){
            int k0 = (c+1)*32;
            rah  = *(const uint4*)(ArH + k0);
            ral  = *(const uint4*)(ArL + k0);
            rwh0 = *(const uint4*)(WrH0 + k0);
            rwl0 = *(const uint4*)(WrL0 + k0);
            rwh1 = *(const uint4*)(WrH1 + k0);
            rwl1 = *(const uint4*)(WrL1 + k0);
        }
        half8 afh[2], afl[2];
        #pragma unroll
        for (int mi = 0; mi < 2; ++mi){
            afh[mi] = *reinterpret_cast<const half8*>(AH_(fks, wr + mi*16 + fr));
            afl[mi] = *reinterpret_cast<const half8*>(AL_(fks, wr + mi*16 + fr));
        }
        #pragma unroll
        for (int ni = 0; ni < 4; ++ni){
            half8 wfh = *reinterpret_cast<const half8*>(WH_(fks, wc + ni*16 + fr));
            half8 wfl = *reinterpret_cast<const half8*>(WL_(fks, wc + ni*16 + fr));
            #pragma unroll
            for (int mi = 0; mi < 2; ++mi){
                acc[mi][ni] = __builtin_amdgcn_mfma_f32_16x16x32_f16(afh[mi], wfh, acc[mi][ni], 0, 0, 0);
                acc[mi][ni] = __builtin_amdgcn_mfma_f32_16x16x32_f16(afh[mi], wfl, acc[mi][ni], 0, 0, 0);
                acc[mi][ni] = __builtin_amdgcn_mfma_f32_16x16x32_f16(afl[mi], wfh, acc[mi][ni], 0, 0, 0);
            }
        }
        if (c + 1 < nc){
            __syncthreads();
            *(uint4*)AH_(aks,arow) = rah;
            *(uint4*)AL_(aks,arow) = ral;
            *(uint4*)WH_(wks0,wrow0) = rwh0;
            *(uint4*)WL_(wks0,wrow0) = rwl0;
            *(uint4*)WH_(wks1,wrow1) = rwh1;
            *(uint4*)WL_(wks1,wrow1) = rwl1;
            __syncthreads();
        }
    }
    if (OUT == 0){
        #pragma unroll
        for (int ni = 0; ni < 4; ++ni){
            int col = n0 + wc + ni*16 + fr;
            float bv = bias ? bias[col] : 0.f;
            #pragma unroll
            for (int mi = 0; mi < 2; ++mi){
                #pragma unroll
                for (int r = 0; r < 4; ++r){
                    int row = m0 + wr + mi*16 + fks*4 + r;
                    float v = acc[mi][ni][r] + bv;
                    if (ACT == 1) v = elu_f(v);
                    Cf[(size_t)row*Nw + col] = v;
                }
            }
        }
    } else {
        __syncthreads();
        #pragma unroll
        for (int ni = 0; ni < 4; ++ni){
            int lc = wc + ni*16 + fr;
            float bv = bias ? bias[n0 + lc] : 0.f;
            #pragma unroll
            for (int mi = 0; mi < 2; ++mi)
                #pragma unroll
                for (int r = 0; r < 4; ++r){
                    int lrow = wr + mi*16 + fks*4 + r;
                    float v = acc[mi][ni][r] + bv;
                    if (ACT == 1) v = elu_f(v);
                    smem[lrow*128 + lc] = f2h(v);
                }
        }
        __syncthreads();
        int colb = (lane & 15)*8;
        #pragma unroll
        for (int it = 0; it < 4; ++it){
            int lrow = w*16 + it*4 + (lane >> 4);
            *(uint4*)&Ch[(size_t)(m0+lrow)*Nw + n0 + colb] = *(uint4*)&smem[lrow*128 + colb];
        }
        __syncthreads();
        #pragma unroll
        for (int ni = 0; ni < 4; ++ni){
            int lc = wc + ni*16 + fr;
            float bv = bias ? bias[n0 + lc] : 0.f;
            #pragma unroll
            for (int mi = 0; mi < 2; ++mi)
                #pragma unroll
                for (int r = 0; r < 4; ++r){
                    int lrow = wr + mi*16 + fks*4 + r;
                    float v = acc[mi][ni][r] + bv;
                    if (ACT == 1) v = elu_f(v);
                    u16 h = f2h(v);
                    smem[lrow*128 + lc] = f2h(v - h2f(h));
                }
        }
        __syncthreads();
        #pragma unroll
        for (int it = 0; it < 4; ++it){
            int lrow = w*16 + it*4 + (lane >> 4);
            *(uint4*)&Cl[(size_t)(m0+lrow)*Nw + n0 + colb] = *(uint4*)&smem[lrow*128 + colb];
        }
    }
    #undef AH_
    #undef AL_
    #undef WH_
    #undef WL_
}

// ---------------------------------------------------------------- f16 MFMA GEMM, double-buffered,
// LDS-staged coalesced u16 epilogue. 1D grid with bijective XCD-chunked swizzle (626 = 8*78 + 2).
template<int ACT>
__global__ __launch_bounds__(256) void k_gemm_f16(const u16* __restrict__ A,
        const u16* __restrict__ Wt, const float* __restrict__ bias,
        float* __restrict__ Cf, u16* __restrict__ Cb, int M, int K, int Nw){
    __shared__ u16 smem[16384];
    #define ALS_(cb,ks,m) (smem +        ((cb)*4096 + (ks)*1024 + (m)*8))
    #define BLS_(cb,ks,m) (smem + 8192 + ((cb)*4096 + (ks)*1024 + (m)*8))
    int tid = threadIdx.x;
    int lane = tid & 63, w = tid >> 6;
    int wr = (w >> 1)*64, wc = (w & 1)*64;
    int lin = blockIdx.x;
    int xcd = lin & 7, jj = lin >> 3;
    int wk = (xcd < 2 ? xcd*79 : 2*79 + (xcd-2)*78) + jj;
    int m0 = (wk >> 1)*128, n0 = (wk & 1)*128;
    int mloc = tid & 127;
    int ksl  = tid >> 7;
    int gmA = m0 + mloc; if (gmA >= M) gmA = M - 1;
    const u16* Arow = A  + (size_t)gmA*K;
    const u16* Brow = Wt + (size_t)(n0 + mloc)*K;
    f32x4_ z = {0.f, 0.f, 0.f, 0.f};
    f32x4_ acc[4][4];
    #pragma unroll
    for (int i = 0; i < 4; ++i)
        #pragma unroll
        for (int j = 0; j < 4; ++j) acc[i][j] = z;
    const int fr = lane & 15, fks = lane >> 4;
    int nc = K >> 5;
    uint4 sa0, sa1, sb0, sb1;

    sa0 = *(const uint4*)(Arow + ksl*8);
    sa1 = *(const uint4*)(Arow + 16 + ksl*8);
    sb0 = *(const uint4*)(Brow + ksl*8);
    sb1 = *(const uint4*)(Brow + 16 + ksl*8);
    *(uint4*)ALS_(0,ksl,  mloc) = sa0;
    *(uint4*)ALS_(0,ksl+2,mloc) = sa1;
    *(uint4*)BLS_(0,ksl,  mloc) = sb0;
    *(uint4*)BLS_(0,ksl+2,mloc) = sb1;
    __syncthreads();

    for (int c = 0; c < nc; ++c){
        if (c + 1 < nc){
            int k0 = (c+1)*32;
            sa0 = *(const uint4*)(Arow + k0 + ksl*8);
            sa1 = *(const uint4*)(Arow + k0 + 16 + ksl*8);
            sb0 = *(const uint4*)(Brow + k0 + ksl*8);
            sb1 = *(const uint4*)(Brow + k0 + 16 + ksl*8);
        }
        int cb = c & 1;
        half8 af[4], bf[4];
        #pragma unroll
        for (int mi = 0; mi < 4; ++mi)
            af[mi] = *reinterpret_cast<const half8*>(ALS_(cb, fks, wr + mi*16 + fr));
        #pragma unroll
        for (int ni = 0; ni < 4; ++ni)
            bf[ni] = *reinterpret_cast<const half8*>(BLS_(cb, fks, wc + ni*16 + fr));
        #pragma unroll
        for (int mi = 0; mi < 4; ++mi)
            #pragma unroll
            for (int ni = 0; ni < 4; ++ni)
                acc[mi][ni] = __builtin_amdgcn_mfma_f32_16x16x32_f16(af[mi], bf[ni], acc[mi][ni], 0, 0, 0);
        if (c + 1 < nc){
            __syncthreads();
            int nb2 = (c+1) & 1;
            *(uint4*)ALS_(nb2,ksl,  mloc) = sa0;
            *(uint4*)ALS_(nb2,ksl+2,mloc) = sa1;
            *(uint4*)BLS_(nb2,ksl,  mloc) = sb0;
            *(uint4*)BLS_(nb2,ksl+2,mloc) = sb1;
            __syncthreads();
        }
    }
    if (Cb){
        __syncthreads();
        #pragma unroll
        for (int ni = 0; ni < 4; ++ni){
            int lc = wc + ni*16 + fr;
            float bv = bias ? bias[n0 + lc] : 0.f;
            #pragma unroll
            for (int mi = 0; mi < 4; ++mi)
                #pragma unroll
                for (int r = 0; r < 4; ++r){
                    int lrow = wr + mi*16 + fks*4 + r;
                    float v = acc[mi][ni][r] + bv;
                    if (ACT == 2) v = selu_f(v);
                    else if (ACT == 3) v = sigmoid_f(v);
                    smem[lrow*128 + lc] = f2h(v);
                }
        }
        __syncthreads();
        int colb = (lane & 15)*8;
        #pragma unroll
        for (int it = 0; it < 8; ++it){
            int lrow = w*32 + it*4 + (lane >> 4);
            int grow = m0 + lrow;
            if (grow < M)
                *(uint4*)&Cb[(size_t)grow*Nw + n0 + colb] = *(uint4*)&smem[lrow*128 + colb];
        }
    } else {
        #pragma unroll
        for (int ni = 0; ni < 4; ++ni){
            int col = n0 + wc + ni*16 + fr;
            float bv = bias ? bias[col] : 0.f;
            #pragma unroll
            for (int mi = 0; mi < 4; ++mi)
                #pragma unroll
                for (int r = 0; r < 4; ++r){
                    int row = m0 + wr + mi*16 + fks*4 + r;
                    if (row < M){
                        float v = acc[mi][ni][r] + bv;
                        if (ACT == 2) v = selu_f(v);
                        else if (ACT == 3) v = sigmoid_f(v);
                        Cf[(size_t)row*Nw + col] = v;
                    }
                }
        }
    }
    #undef ALS_
    #undef BLS_
}

// ---------------------------------------------------------------- fused gate/het/hom f16 MFMA GEMM,
// LDS-staged coalesced u16 epilogue. 1D grid with bijective XCD-chunked swizzle (1878 = 8*234 + 6).
__global__ __launch_bounds__(256) void k_gemm_f16x3(const u16* __restrict__ A,
        const u16* __restrict__ Wtcat, const float* __restrict__ bt,
        u16* __restrict__ G, u16* __restrict__ Hh, u16* __restrict__ Hm, int M){
    const int K = H_;
    __shared__ u16 smem[16384];
    #define ALS_(cb,ks,m) (smem +        ((cb)*4096 + (ks)*1024 + (m)*8))
    #define BLS_(cb,ks,m) (smem + 8192 + ((cb)*4096 + (ks)*1024 + (m)*8))
    int tid = threadIdx.x;
    int lane = tid & 63, w = tid >> 6;
    int wr = (w >> 1)*64, wc = (w & 1)*64;
    int lin = blockIdx.x;
    int xcd = lin & 7, jj = lin >> 3;
    int wk = (xcd < 6 ? xcd*235 : 6*235 + (xcd-6)*234) + jj;
    int m0 = (wk/6)*128;
    int yy = wk % 6;
    int seg = yy >> 1;
    u16* Cb = seg == 0 ? G : (seg == 1 ? Hh : Hm);
    int c0 = (yy & 1)*128;
    int n0 = yy*128;
    int mloc = tid & 127;
    int ksl  = tid >> 7;
    int gmA = m0 + mloc; if (gmA >= M) gmA = M - 1;
    const u16* Arow = A     + (size_t)gmA*K;
    const u16* Brow = Wtcat + (size_t)(n0 + mloc)*K;
    f32x4_ z = {0.f, 0.f, 0.f, 0.f};
    f32x4_ acc[4][4];
    #pragma unroll
    for (int i = 0; i < 4; ++i)
        #pragma unroll
        for (int j = 0; j < 4; ++j) acc[i][j] = z;
    const int fr = lane & 15, fks = lane >> 4;
    const int nc = K >> 5;
    uint4 sa0, sa1, sb0, sb1;
    sa0 = *(const uint4*)(Arow + ksl*8);
    sa1 = *(const uint4*)(Arow + 16 + ksl*8);
    sb0 = *(const uint4*)(Brow + ksl*8);
    sb1 = *(const uint4*)(Brow + 16 + ksl*8);
    *(uint4*)ALS_(0,ksl,  mloc) = sa0;
    *(uint4*)ALS_(0,ksl+2,mloc) = sa1;
    *(uint4*)BLS_(0,ksl,  mloc) = sb0;
    *(uint4*)BLS_(0,ksl+2,mloc) = sb1;
    __syncthreads();
    for (int c = 0; c < nc; ++c){
        if (c + 1 < nc){
            int k0 = (c+1)*32;
            sa0 = *(const uint4*)(Arow + k0 + ksl*8);
            sa1 = *(const uint4*)(Arow + k0 + 16 + ksl*8);
            sb0 = *(const uint4*)(Brow + k0 + ksl*8);
            sb1 = *(const uint4*)(Brow + k0 + 16 + ksl*8);
        }
        int cb = c & 1;
        half8 af[4], bf[4];
        #pragma unroll
        for (int mi = 0; mi < 4; ++mi)
            af[mi] = *reinterpret_cast<const half8*>(ALS_(cb, fks, wr + mi*16 + fr));
        #pragma unroll
        for (int ni = 0; ni < 4; ++ni)
            bf[ni] = *reinterpret_cast<const half8*>(BLS_(cb, fks, wc + ni*16 + fr));
        #pragma unroll
        for (int mi = 0; mi < 4; ++mi)
            #pragma unroll
            for (int ni = 0; ni < 4; ++ni)
                acc[mi][ni] = __builtin_amdgcn_mfma_f32_16x16x32_f16(af[mi], bf[ni], acc[mi][ni], 0, 0, 0);
        if (c + 1 < nc){
            __syncthreads();
            int nb2 = (c+1) & 1;
            *(uint4*)ALS_(nb2,ksl,  mloc) = sa0;
            *(uint4*)ALS_(nb2,ksl+2,mloc) = sa1;
            *(uint4*)BLS_(nb2,ksl,  mloc) = sb0;
            *(uint4*)BLS_(nb2,ksl+2,mloc) = sb1;
            __syncthreads();
        }
    }
    __syncthreads();
    #pragma unroll
    for (int ni = 0; ni < 4; ++ni){
        int lc = wc + ni*16 + fr;
        float bv = (seg == 0 && bt) ? bt[c0 + lc] : 0.f;
        #pragma unroll
        for (int mi = 0; mi < 4; ++mi)
            #pragma unroll
            for (int r = 0; r < 4; ++r){
                int lrow = wr + mi*16 + fks*4 + r;
                float v = acc[mi][ni][r] + bv;
                if (seg == 0) v = sigmoid_f(v);
                smem[lrow*128 + lc] = f2h(v);
            }
    }
    __syncthreads();
    int colb = (lane & 15)*8;
    #pragma unroll
    for (int it = 0; it < 8; ++it){
        int lrow = w*32 + it*4 + (lane >> 4);
        int grow = m0 + lrow;
        if (grow < M)
            *(uint4*)&Cb[(size_t)grow*H_ + c0 + colb] = *(uint4*)&smem[lrow*128 + colb];
    }
    #undef ALS_
    #undef BLS_
}

// ---------------------------------------------------------------- small-N GEMM (f16 A, fp32 W), Nw=8 or 3
__global__ void k_gemm_small(const u16* __restrict__ A, const float* __restrict__ W,
        const float* __restrict__ bias, float* __restrict__ C, int M, int K, int Nw){
    int t = blockIdx.x*blockDim.x + threadIdx.x;
    if (t >= M*Nw) return;
    int m = t / Nw, c = t % Nw;
    const u16* a = A + (size_t)m*K;
    float acc = 0.f;
    for (int k = 0; k < K; k += 8){
        uint4 u = *(const uint4*)(a + k);
        const u16* us = (const u16*)&u;
        #pragma unroll
        for (int j = 0; j < 8; ++j) acc += h2f(us[j]) * W[(k+j)*Nw + c];
    }
    C[t] = acc + bias[c];
}

// ---------------------------------------------------------------- LSH bin assignment: one wave per row
__global__ __launch_bounds__(256) void k_bins(const float* __restrict__ xd,
        const float* __restrict__ Rt, int* __restrict__ bin_idx){
    int g = blockIdx.x*4 + (threadIdx.x >> 6);
    int lane = threadIdx.x & 63;
    const float4* p = (const float4*)(xd + (size_t)g*H_);
    float4 x = p[lane];
    float acc[5];
    #pragma unroll
    for (int j = 0; j < 5; ++j){
        float4 r = ((const float4*)(Rt + j*H_))[lane];
        acc[j] = x.x*r.x + x.y*r.y + x.z*r.z + x.w*r.w;
    }
    #pragma unroll
    for (int off = 32; off; off >>= 1)
        #pragma unroll
        for (int j = 0; j < 5; ++j) acc[j] += __shfl_xor(acc[j], off, 64);
    if (lane == 0){
        float best = acc[0]; int bi = 0;
        #pragma unroll
        for (int j = 1; j < 5; ++j) if (acc[j] > best){ best = acc[j]; bi = j; }
        #pragma unroll
        for (int j = 0; j < 5; ++j){ float v = -acc[j]; if (v > best){ best = v; bi = 5 + j; } }
        bin_idx[g] = bi;
    }
}

// ---------------------------------------------------------------- stable counting sort (per batch)
__global__ __launch_bounds__(256) void k_sort(const int* __restrict__ bin_idx,
                                              int* __restrict__ order){
    int b = blockIdx.x;
    const int* bi = bin_idx + b*N_;
    int* ord = order + b*N_;
    __shared__ int cnt[256][NBINS];
    __shared__ int binoff[NBINS];
    int t = threadIdx.x;
    const int CH = (N_ + 255)/256;  // 20
    int lo = t*CH, hi = lo+CH < N_ ? lo+CH : N_;
    for (int j = 0; j < NBINS; ++j) cnt[t][j] = 0;
    for (int n = lo; n < hi; ++n) cnt[t][bi[n]]++;
    __syncthreads();
    if (t < NBINS){
        int run = 0;
        for (int q = 0; q < 256; ++q){ int v = cnt[q][t]; cnt[q][t] = run; run += v; }
        binoff[t] = run;
    }
    __syncthreads();
    if (t == 0){
        int run = 0;
        for (int j = 0; j < NBINS; ++j){ int v = binoff[j]; binoff[j] = run; run += v; }
    }
    __syncthreads();
    for (int n = lo; n < hi; ++n){
        int v = bi[n];
        int pos = binoff[v] + cnt[t][v]++;
        ord[pos] = n;
    }
}

// ---------------------------------------------------------------- gather points into bin order,
// split into f16 hi/lo (Markidis), plus fp32 squared norm
__global__ __launch_bounds__(256) void k_gather(const float* __restrict__ xd,
        const int* __restrict__ order, u16* __restrict__ xh, u16* __restrict__ xl,
        float* __restrict__ sqg){
    int g = blockIdx.x*4 + (threadIdx.x >> 6);
    int lane = threadIdx.x & 63;
    int b = g / N_;
    int node = order[g];
    const float4* src = (const float4*)(xd + ((size_t)b*N_ + node)*H_);
    float4 v = src[lane];
    unsigned hw0, hw1, lw0, lw1;
    {
        u16 h0 = f2h(v.x), h1 = f2h(v.y), h2 = f2h(v.z), h3 = f2h(v.w);
        u16 l0 = f2h(v.x - h2f(h0)), l1 = f2h(v.y - h2f(h1));
        u16 l2 = f2h(v.z - h2f(h2)), l3 = f2h(v.w - h2f(h3));
        hw0 = (unsigned)h0 | ((unsigned)h1 << 16);
        hw1 = (unsigned)h2 | ((unsigned)h3 << 16);
        lw0 = (unsigned)l0 | ((unsigned)l1 << 16);
        lw1 = (unsigned)l2 | ((unsigned)l3 << 16);
    }
    uint2 hw = {hw0, hw1}, lw = {lw0, lw1};
    *(uint2*)(xh + (size_t)g*H_ + lane*4) = hw;
    *(uint2*)(xl + (size_t)g*H_ + lane*4) = lw;
    float s = v.x*v.x + v.y*v.y + v.z*v.z + v.w*v.w;
    #pragma unroll
    for (int off = 32; off; off >>= 1) s += __shfl_xor(s, off, 64);
    if (lane == 0) sqg[g] = s;
}

// ---------------------------------------------------------------- distance-matrix via split-f16 MFMA
// dot = hi.hi + hi.lo + lo.hi (fp32 accum); writes RAW d2 (exp applied in k_sel).
// Register prefetch of next K-chunk; sq values in REGISTERS (loads retire under K loop)
// -> LDS exactly 32 KB. __launch_bounds__(256,5) caps VGPR at <=102 so 5 blocks/CU
// co-reside = grid(1280)/256CU exactly -> no straggler tail (r18's miss was VGPR=104).
__global__ __launch_bounds__(256, 5) void k_dist(const u16* __restrict__ xh,
        const u16* __restrict__ xl, const float* __restrict__ sqg,
        float* __restrict__ dm){
    int lin = blockIdx.x;
    int wk = (lin & 7)*160 + (lin >> 3);   // chunked XCD transform (1280/8 = 160)
    int binlin = wk >> 4;
    int tile = wk & 15;
    int tr = (tile >> 2)*128, tc = (tile & 3)*128;
    const u16* xhb = xh + (size_t)binlin*BINSZ*H_;
    const u16* xlb = xl + (size_t)binlin*BINSZ*H_;
    const float* sqb = sqg + binlin*BINSZ;
    __shared__ u16 Ah[4][128][8], Al[4][128][8];
    __shared__ u16 Bh[4][128][8], Bl[4][128][8];
    int tid = threadIdx.x;
    int lane = tid & 63, w = tid >> 6;
    int wr = (w >> 1)*64, wc = (w & 1)*64;
    int mloc = tid & 127, ksl = tid >> 7;
    int rA = tr + mloc; if (rA >= BINSZ) rA = BINSZ-1;
    int rC = tc + mloc; if (rC >= BINSZ) rC = BINSZ-1;
    const u16* ArH = xhb + (size_t)rA*H_ + ksl*8;
    const u16* ArL = xlb + (size_t)rA*H_ + ksl*8;
    const u16* BrH = xhb + (size_t)rC*H_ + ksl*8;
    const u16* BrL = xlb + (size_t)rC*H_ + ksl*8;
    f32x4_ z = {0.f, 0.f, 0.f, 0.f};
    f32x4_ acc[4][4];
    #pragma unroll
    for (int i = 0; i < 4; ++i)
        #pragma unroll
        for (int j = 0; j < 4; ++j) acc[i][j] = z;
    const int fr = lane & 15, fks = lane >> 4;

    // epilogue sq values -> registers now; loads retire under the K loop
    float sqrv[4][4], sqcv[4];
    #pragma unroll
    for (int mi = 0; mi < 4; ++mi)
        #pragma unroll
        for (int r = 0; r < 4; ++r){
            int rg = tr + wr + mi*16 + fks*4 + r;
            sqrv[mi][r] = sqb[rg < BINSZ ? rg : BINSZ-1];
        }
    #pragma unroll
    for (int ni = 0; ni < 4; ++ni){
        int c = tc + wc + ni*16 + fr;
        sqcv[ni] = sqb[c < BINSZ ? c : BINSZ-1];
    }

    uint4 pah0, pah1, pal0, pal1, pbh0, pbh1, pbl0, pbl1;
    pah0 = *(const uint4*)(ArH);      pah1 = *(const uint4*)(ArH + 16);
    pal0 = *(const uint4*)(ArL);      pal1 = *(const uint4*)(ArL + 16);
    pbh0 = *(const uint4*)(BrH);      pbh1 = *(const uint4*)(BrH + 16);
    pbl0 = *(const uint4*)(BrL);      pbl1 = *(const uint4*)(BrL + 16);
    *(uint4*)(&Ah[ksl  ][mloc][0]) = pah0;
    *(uint4*)(&Ah[ksl+2][mloc][0]) = pah1;
    *(uint4*)(&Al[ksl  ][mloc][0]) = pal0;
    *(uint4*)(&Al[ksl+2][mloc][0]) = pal1;
    *(uint4*)(&Bh[ksl  ][mloc][0]) = pbh0;
    *(uint4*)(&Bh[ksl+2][mloc][0]) = pbh1;
    *(uint4*)(&Bl[ksl  ][mloc][0]) = pbl0;
    *(uint4*)(&Bl[ksl+2][mloc][0]) = pbl1;
    __syncthreads();

    const int NCH = H_/32;   // 8
    for (int cc = 0; cc < NCH; ++cc){
        if (cc + 1 < NCH){
            int k0 = (cc+1)*32;
            pah0 = *(const uint4*)(ArH + k0);      pah1 = *(const uint4*)(ArH + k0 + 16);
            pal0 = *(const uint4*)(ArL + k0);      pal1 = *(const uint4*)(ArL + k0 + 16);
            pbh0 = *(const uint4*)(BrH + k0);      pbh1 = *(const uint4*)(BrH + k0 + 16);
            pbl0 = *(const uint4*)(BrL + k0);      pbl1 = *(const uint4*)(BrL + k0 + 16);
        }
        half8 afh[4], afl[4];
        #pragma unroll
        for (int mi = 0; mi < 4; ++mi){
            afh[mi] = *reinterpret_cast<const half8*>(&Ah[fks][wr + mi*16 + fr][0]);
            afl[mi] = *reinterpret_cast<const half8*>(&Al[fks][wr + mi*16 + fr][0]);
        }
        #pragma unroll
        for (int ni = 0; ni < 4; ++ni){
            half8 bfh = *reinterpret_cast<const half8*>(&Bh[fks][wc + ni*16 + fr][0]);
            half8 bfl = *reinterpret_cast<const half8*>(&Bl[fks][wc + ni*16 + fr][0]);
            #pragma unroll
            for (int mi = 0; mi < 4; ++mi){
                acc[mi][ni] = __builtin_amdgcn_mfma_f32_16x16x32_f16(afh[mi], bfh, acc[mi][ni], 0, 0, 0);
                acc[mi][ni] = __builtin_amdgcn_mfma_f32_16x16x32_f16(afh[mi], bfl, acc[mi][ni], 0, 0, 0);
                acc[mi][ni] = __builtin_amdgcn_mfma_f32_16x16x32_f16(afl[mi], bfh, acc[mi][ni], 0, 0, 0);
            }
        }
        if (cc + 1 < NCH){
            __syncthreads();
            *(uint4*)(&Ah[ksl  ][mloc][0]) = pah0;
            *(uint4*)(&Ah[ksl+2][mloc][0]) = pah1;
            *(uint4*)(&Al[ksl  ][mloc][0]) = pal0;
            *(uint4*)(&Al[ksl+2][mloc][0]) = pal1;
            *(uint4*)(&Bh[ksl  ][mloc][0]) = pbh0;
            *(uint4*)(&Bh[ksl+2][mloc][0]) = pbh1;
            *(uint4*)(&Bl[ksl  ][mloc][0]) = pbl0;
            *(uint4*)(&Bl[ksl+2][mloc][0]) = pbl1;
            __syncthreads();
        }
    }
    #pragma unroll
    for (int mi = 0; mi < 4; ++mi){
        #pragma unroll
        for (int r = 0; r < 4; ++r){
            int rg = tr + wr + mi*16 + fks*4 + r;
            if (rg >= BINSZ) continue;
            float sr = sqrv[mi][r];
            #pragma unroll
            for (int ni = 0; ni < 4; ++ni){
                int c = tc + wc + ni*16 + fr;
                if (c >= BINSZ) continue;
                float d2 = sr - 2.f*acc[mi][ni][r] + sqcv[ni];
                dm[((size_t)binlin*BINSZ + rg)*BINSZ + c] = d2;
            }
        }
    }
}

// ---------------------------------------------------------------- top-16 selection, TWO rows per wave
// (32 lanes/row). 16 candidates/lane in NAMED u64 regs (d2_bits<<32)|idx, bitonic-sorted
// ascending; per round ONE 5-step u64 shfl-min + shift-extract. u64-min == reference tie-break.
// Block swizzle: batch = lin&7, reverse bin order (neutral but harmless; kept from r23).
__global__ __launch_bounds__(256) void k_sel(const float* __restrict__ dmraw,
        const int* __restrict__ order,
        int* __restrict__ nbr_idx, float* __restrict__ nbr_val,
        float* __restrict__ nrm){
    int lin = blockIdx.x;
    int bb = lin & 7;
    int jj = lin >> 3;                     // 0..624
    int lane = threadIdx.x & 63;
    int half = lane >> 5;
    int l32  = lane & 31;
    int g = bb*N_ + (N_ - 8 - jj*8) + (threadIdx.x >> 6)*2 + half;
    int b = g / N_, pos = g % N_;
    int bin = pos / BINSZ, r = pos % BINSZ;
    int binlin = b*NBINS + bin;
    const float* row = dmraw + ((size_t)binlin*BINSZ + r)*BINSZ;

    typedef unsigned long long u64;
    #define LOADK(i) u64 k##i; { int c = l32 + (i)*32; \
        if (c < BINSZ){ unsigned db = __float_as_uint(fmaxf(row[c], 1e-6f)); \
            k##i = ((u64)db << 32) | (unsigned)c; } else k##i = ~0ull; }
    LOADK(0) LOADK(1) LOADK(2)  LOADK(3)  LOADK(4)  LOADK(5)  LOADK(6)  LOADK(7)
    LOADK(8) LOADK(9) LOADK(10) LOADK(11) LOADK(12) LOADK(13) LOADK(14) LOADK(15)
    #undef LOADK

    #define CSU(a,b) { u64 mn_ = a < b ? a : b; u64 mx_ = a < b ? b : a; a = mn_; b = mx_; }
    #define CSD(a,b) { u64 mn_ = a < b ? a : b; u64 mx_ = a < b ? b : a; a = mx_; b = mn_; }
    CSU(k0,k1) CSD(k2,k3) CSU(k4,k5) CSD(k6,k7) CSU(k8,k9) CSD(k10,k11) CSU(k12,k13) CSD(k14,k15)
    CSU(k0,k2) CSU(k1,k3) CSD(k4,k6) CSD(k5,k7) CSU(k8,k10) CSU(k9,k11) CSD(k12,k14) CSD(k13,k15)
    CSU(k0,k1) CSU(k2,k3) CSD(k4,k5) CSD(k6,k7) CSU(k8,k9) CSU(k10,k11) CSD(k12,k13) CSD(k14,k15)
    CSU(k0,k4) CSU(k1,k5) CSU(k2,k6) CSU(k3,k7) CSD(k8,k12) CSD(k9,k13) CSD(k10,k14) CSD(k11,k15)
    CSU(k0,k2) CSU(k1,k3) CSU(k4,k6) CSU(k5,k7) CSD(k8,k10) CSD(k9,k11) CSD(k12,k14) CSD(k13,k15)
    CSU(k0,k1) CSU(k2,k3) CSU(k4,k5) CSU(k6,k7) CSD(k8,k9) CSD(k10,k11) CSD(k12,k13) CSD(k14,k15)
    CSU(k0,k8) CSU(k1,k9) CSU(k2,k10) CSU(k3,k11) CSU(k4,k12) CSU(k5,k13) CSU(k6,k14) CSU(k7,k15)
    CSU(k0,k4) CSU(k1,k5) CSU(k2,k6)  CSU(k3,k7)  CSU(k8,k12) CSU(k9,k13) CSU(k10,k14) CSU(k11,k15)
    CSU(k0,k2) CSU(k1,k3) CSU(k4,k6)  CSU(k5,k7)  CSU(k8,k10) CSU(k9,k11) CSU(k12,k14) CSU(k13,k15)
    CSU(k0,k1) CSU(k2,k3) CSU(k4,k5)  CSU(k6,k7)  CSU(k8,k9)  CSU(k10,k11) CSU(k12,k13) CSU(k14,k15)
    #undef CSU
    #undef CSD

    u64 mykey = ~0ull;
    #pragma unroll
    for (int rr = 0; rr < KNN; ++rr){
        u64 m = k0;
        #pragma unroll
        for (int off = 16; off; off >>= 1){
            u64 o = __shfl_xor(m, off, 64);
            if (o < m) m = o;
        }
        if (l32 == rr) mykey = m;
        bool win = (k0 == m);
        k0  = win ? k1  : k0;
        k1  = win ? k2  : k1;
        k2  = win ? k3  : k2;
        k3  = win ? k4  : k3;
        k4  = win ? k5  : k4;
        k5  = win ? k6  : k5;
        k6  = win ? k7  : k6;
        k7  = win ? k8  : k7;
        k8  = win ? k9  : k8;
        k9  = win ? k10 : k9;
        k10 = win ? k11 : k10;
        k11 = win ? k12 : k11;
        k12 = win ? k13 : k12;
        k13 = win ? k14 : k13;
        k14 = win ? k15 : k14;
        k15 = win ? ~0ull : k15;
    }
    float myd = __uint_as_float((unsigned)(mykey >> 32));
    int myc = (int)(unsigned)(mykey & 0xFFFFFFFFull);
    float myv = (l32 < KNN) ? expf(-0.1f*sqrtf(myd)) : 0.f;
    float deg = myv;
    #pragma unroll
    for (int off = 16; off; off >>= 1) deg += __shfl_xor(deg, off, 64);
    const int* ord = order + b*N_ + bin*BINSZ;
    int node_i = ord[r];
    if (l32 < KNN){
        nbr_idx[((size_t)b*N_ + node_i)*KNN + l32] = ord[myc];
        nbr_val[((size_t)b*N_ + node_i)*KNN + l32] = myv;
    }
    if (l32 == 0) nrm[b*N_ + node_i] = 1.f/sqrtf(deg + 1e-6f);
}

// ---------------------------------------------------------------- GHConv combine (f16 in, f16 out)
// batch-per-XCD block swizzle: M_TOT = 8*5000 exactly; node = (lin&7)*5000 + (lin>>3)
// puts each batch's 2.56MB hom slice on ONE XCD's 4MB L2 -> neighbor gathers L2-hit.
__global__ __launch_bounds__(256) void k_ghconv(const u16* __restrict__ gate,
        const u16* __restrict__ het, const u16* __restrict__ hom,
        const int* __restrict__ nbr_idx, const float* __restrict__ nbr_val,
        const float* __restrict__ nrm, u16* __restrict__ out){
    int lin = blockIdx.x;
    int node = (lin & 7)*N_ + (lin >> 3);
    int b = lin & 7;
    int t = threadIdx.x;
    __shared__ int nid[KNN];
    __shared__ float nv[KNN];
    if (t < KNN){
        int d = nbr_idx[(size_t)node*KNN + t];
        nid[t] = d;
        nv[t] = nbr_val[(size_t)node*KNN + t] * nrm[b*N_ + d];
    }
    __syncthreads();
    float acc = 0.f;
    #pragma unroll
    for (int k = 0; k < KNN; ++k)
        acc += nv[k] * h2f(hom[((size_t)b*N_ + nid[k])*H_ + t]);
    float ni = nrm[node];
    float g = h2f(gate[(size_t)node*H_ + t]);
    float v = g * (ni * acc) + (1.f - g) * h2f(het[(size_t)node*H_ + t]);
    out[(size_t)node*H_ + t] = f2h(selu_f(v));
}

// ---------------------------------------------------------------- xr concat -> f16 [M][64] zero-padded
__global__ void k_xr(const float* __restrict__ enc, const float* __restrict__ logits,
                     u16* __restrict__ xr_h){
    int i = blockIdx.x*blockDim.x + threadIdx.x;
    if (i >= M_TOT) return;
    const float* e = enc + (size_t)i*ENCD;
    const float* l = logits + (size_t)i*NCOUT;
    u16* x = xr_h + (size_t)i*64;
    #pragma unroll
    for (int j = 0; j < ENCD; ++j) x[j] = f2h(e[j]);
    #pragma unroll
    for (int j = 0; j < NCOUT; ++j) x[ENCD+j] = f2h(l[j]);
    #pragma unroll
    for (int j = XRD; j < 64; ++j) x[j] = 0;
}

// ----------------------------------------------------------------
extern "C" void kernel_launch(void* const* d_in, const int* in_sizes, int n_in,
                              void* d_out, int out_size, void* d_ws, size_t ws_size,
                              hipStream_t stream){
    const float* X        = (const float*)d_in[0];
    const float* ffn1_w   = (const float*)d_in[1];
    const float* ffn1_b   = (const float*)d_in[2];
    const float* ffn2_w   = (const float*)d_in[3];
    const float* ffn2_b   = (const float*)d_in[4];
    const float* R        = (const float*)d_in[5];
    const float* enc_id_w = (const float*)d_in[6];
    const float* enc_id_b = (const float*)d_in[7];
    const float* wt_id    = (const float*)d_in[8];
    const float* bt_id    = (const float*)d_in[9];
    const float* wh_id    = (const float*)d_in[10];
    const float* theta_id = (const float*)d_in[11];
    const float* dec_id_w = (const float*)d_in[12];
    const float* dec_id_b = (const float*)d_in[13];
    const float* out_id_w = (const float*)d_in[14];
    const float* out_id_b = (const float*)d_in[15];
    const float* enc_reg_w= (const float*)d_in[16];
    const float* enc_reg_b= (const float*)d_in[17];
    const float* wt_reg   = (const float*)d_in[18];
    const float* bt_reg   = (const float*)d_in[19];
    const float* wh_reg   = (const float*)d_in[20];
    const float* theta_reg= (const float*)d_in[21];
    const float* dec_reg_w= (const float*)d_in[22];
    const float* dec_reg_b= (const float*)d_in[23];
    const float* out_reg_w= (const float*)d_in[24];
    const float* out_reg_b= (const float*)d_in[25];

    float* out_logits = (float*)d_out;
    float* out_mom    = (float*)d_out + (size_t)M_TOT*NCOUT;

    float* ws = (float*)d_ws;
    size_t o = 0;
    float* enc  = ws + o; o += (size_t)M_TOT*ENCD;
    float* bufC = ws + o; o += (size_t)M_TOT*H_;   // h1 hi/lo -> xh/xl -> gate_h+het_h
    float* bufB = ws + o; o += (size_t)M_TOT*H_;   // x_dist -> dm(part1) -> hom_h
    float* bufD = ws + o; o += (size_t)M_TOT*H_;   // dm(part2)
    float* sqg  = ws + o; o += M_TOT;
    float* nrm  = ws + o; o += M_TOT;
    float* nbrv = ws + o; o += (size_t)M_TOT*KNN;
    float* Rt   = ws + o; o += 5*H_;
    int* ibase   = (int*)(ws + o);
    o += (size_t)18*M_TOT;
    int* bin_idx = ibase;
    int* order   = ibase + M_TOT;
    int* nbr_idx = ibase + 2*M_TOT;
    u16* hbase = (u16*)(ws + o);
    size_t ho = 0;
    u16* enc_h = hbase + ho; ho += (size_t)M_TOT*32;
    u16* enc_l = hbase + ho; ho += (size_t)M_TOT*32;
    u16* xr_h  = hbase + ho; ho += (size_t)M_TOT*64;
    u16* hA_h  = hbase + ho; ho += (size_t)M_TOT*H_;
    u16* h1_h  = hbase + ho; ho += (size_t)M_TOT*H_;
    u16* wt_encid  = hbase + ho; ho += 256*32;
    u16* wt_encreg = hbase + ho; ho += 256*64;
    u16* wtcat_id  = hbase + ho; ho += (size_t)768*256;
    u16* dec_id_h  = hbase + ho; ho += (size_t)256*256;
    u16* wtcat_reg = hbase + ho; ho += (size_t)768*256;
    u16* dec_reg_h = hbase + ho; ho += (size_t)256*256;
    u16* wf1h = hbase + ho; ho += 256*32;
    u16* wf1l = hbase + ho; ho += 256*32;
    u16* wf2h = hbase + ho; ho += (size_t)256*256;
    u16* wf2l = hbase + ho; ho += (size_t)256*256;
    // aliases into dead regions
    u16* h1h = (u16*)bufC;                // ffn1 out hi [M][256], live ffn1..ffn2
    u16* h1l = h1h + (size_t)M_TOT*H_;    // ffn1 out lo
    u16* xh = (u16*)bufC;                 // gathered hi f16 [M][256], live gather..dist
    u16* xl = xh + (size_t)M_TOT*H_;      // gathered lo f16
    float* dm = bufB;                     // raw d2, 80 MB spans bufB+bufD, live dist..sel
    u16* gate_h = (u16*)bufC;             // live after sel (xh/xl dead)
    u16* het_h  = gate_h + (size_t)M_TOT*H_;
    u16* hom_h  = (u16*)bufB;             // live after sel (dm dead)

    PrepArgs pa;
    const float* srcs[NPREP] = {enc_id_w, enc_reg_w, wt_id, wh_id, theta_id, dec_id_w,
                                wt_reg, wh_reg, theta_reg, dec_reg_w,
                                ffn1_w, ffn1_w, ffn2_w, ffn2_w};
    u16* dsts[NPREP] = {wt_encid, wt_encreg, wtcat_id, wtcat_id + 65536, wtcat_id + 131072,
                        dec_id_h, wtcat_reg, wtcat_reg + 65536, wtcat_reg + 131072, dec_reg_h,
                        wf1h, wf1l, wf2h, wf2l};
    int Ks[NPREP]  = {ENCD, XRD, H_, H_, H_, H_, H_, H_, H_, H_, ENCD, ENCD, H_, H_};
    int Kas[NPREP] = {32, 64, H_, H_, H_, H_, H_, H_, H_, H_, 32, 32, H_, H_};
    int los[NPREP] = {0,0,0,0,0,0,0,0,0,0, 0,1,0,1};
    int acc_blk = 0;
    for (int i = 0; i < NPREP; ++i){
        pa.src[i] = srcs[i]; pa.dst[i] = dsts[i]; pa.K[i] = Ks[i]; pa.Ka[i] = Kas[i];
        pa.lo[i] = los[i];
        acc_blk += Kas[i];
        pa.blk_end[i] = acc_blk;
    }

    dim3 b256(256);
    int nb = (M_TOT + 255)/256;
    dim3 gf(M_TOT/64, H_/128);            // k_ffn grid (625, 2)

    k_prep<<<acc_blk, b256, 0, stream>>>(pa);
    k_prepR<<<5, b256, 0, stream>>>(R, Rt);
    k_encode<<<nb, b256, 0, stream>>>(X, enc, enc_h, enc_l);

    // ---- x_dist chain (split-f16 MFMA, fp32-equivalent accuracy)
    k_ffn<1,1><<<gf, b256, 0, stream>>>(enc_h, enc_l, wf1h, wf1l, ffn1_b,
                                        nullptr, h1h, h1l, M_TOT, 32, H_);
    k_ffn<0,0><<<gf, b256, 0, stream>>>(h1h, h1l, wf2h, wf2l, ffn2_b,
                                        bufB, nullptr, nullptr, M_TOT, H_, H_);

    // ---- graph build
    k_bins<<<M_TOT/4, b256, 0, stream>>>(bufB, Rt, bin_idx);
    k_sort<<<B_, b256, 0, stream>>>(bin_idx, order);
    k_gather<<<M_TOT/4, b256, 0, stream>>>(bufB, order, xh, xl, sqg);
    k_dist<<<1280, b256, 0, stream>>>(xh, xl, sqg, dm);
    k_sel<<<M_TOT/8, b256, 0, stream>>>(dm, order, nbr_idx, nbrv, nrm);

    // ---- id branch (f16 MFMA; 1D swizzled grids)
    k_gemm_f16<2><<<626, b256, 0, stream>>>(enc_h, wt_encid, enc_id_b, nullptr, hA_h, M_TOT, 32, H_);
    k_gemm_f16x3<<<1878, b256, 0, stream>>>(hA_h, wtcat_id, bt_id, gate_h, het_h, hom_h, M_TOT);
    k_ghconv<<<M_TOT, b256, 0, stream>>>(gate_h, het_h, hom_h, nbr_idx, nbrv, nrm, h1_h);
    k_gemm_f16<2><<<626, b256, 0, stream>>>(h1_h, dec_id_h, dec_id_b, nullptr, hA_h, M_TOT, H_, H_);
    k_gemm_small<<<(M_TOT*NCOUT + 255)/256, b256, 0, stream>>>(hA_h, out_id_w, out_id_b,
                                                               out_logits, M_TOT, H_, NCOUT);

    // ---- reg branch (f16 MFMA; 1D swizzled grids)
    k_xr<<<nb, b256, 0, stream>>>(enc, out_logits, xr_h);
    k_gemm_f16<2><<<626, b256, 0, stream>>>(xr_h, wt_encreg, enc_reg_b, nullptr, h1_h, M_TOT, 64, H_);
    k_gemm_f16x3<<<1878, b256, 0, stream>>>(h1_h, wtcat_reg, bt_reg, gate_h, het_h, hom_h, M_TOT);
    k_ghconv<<<M_TOT, b256, 0, stream>>>(gate_h, het_h, hom_h, nbr_idx, nbrv, nrm, hA_h);
    k_gemm_f16<2><<<626, b256, 0, stream>>>(hA_h, dec_reg_h, dec_reg_b, nullptr, h1_h, M_TOT, H_, H_);
    k_gemm_small<<<(M_TOT*NMOM + 255)/256, b256, 0, stream>>>(h1_h, out_reg_w, out_reg_b,
                                                              out_mom, M_TOT, H_, NMOM);

    (void)in_sizes; (void)n_in; (void)out_size; (void)ws_size;
}

// Round 25
// 488.191 us; speedup vs baseline: 1.4567x; 1.4567x over previous
//
#include <hip/hip_runtime.h>
#include <math.h>

#define B_    8
#define N_    5000
#define F_    15
#define NCIN  12
#define NCOUT 8
#define NMOM  3
#define H_    256
#define BINSZ 500
#define NBINS 10
#define KNN   16
#define ENCD  26   // NCIN + (F-1)
#define XRD   34   // ENCD + NCOUT
#define M_TOT (B_*N_)  // 40000

typedef unsigned short u16;
typedef _Float16 half8 __attribute__((ext_vector_type(8)));
typedef float f32x4_ __attribute__((ext_vector_type(4)));

__device__ __forceinline__ float elu_f(float x){ return x > 0.f ? x : expm1f(x); }
__device__ __forceinline__ float selu_f(float x){
    const float scale = 1.0507009873554804934193349852946f;
    const float alpha = 1.6732632423543772848170429916717f;
    return x > 0.f ? scale*x : scale*alpha*expm1f(x);
}
__device__ __forceinline__ float sigmoid_f(float x){ return 1.f/(1.f+expf(-x)); }
__device__ __forceinline__ u16 f2h(float x){ _Float16 h = (_Float16)x; return __builtin_bit_cast(u16, h); }
__device__ __forceinline__ float h2f(u16 u){ return (float)__builtin_bit_cast(_Float16, u); }

// ---------------------------------------------------------------- encode (fp32 + f16 hi/lo)
__global__ void k_encode(const float* __restrict__ X, float* __restrict__ enc,
                         u16* __restrict__ enc_h, u16* __restrict__ enc_l){
    int i = blockIdx.x*blockDim.x + threadIdx.x;
    if (i >= M_TOT) return;
    const float* x = X + (size_t)i*F_;
    float* e = enc + (size_t)i*ENCD;
    u16* eh = enc_h + (size_t)i*32;
    u16* el = enc_l + (size_t)i*32;
    int id = (int)x[0];
    #pragma unroll
    for (int c = 0; c < NCIN; ++c){
        float v = (c == id) ? 1.f : 0.f;
        e[c] = v; eh[c] = f2h(v); el[c] = 0;
    }
    #pragma unroll
    for (int f = 1; f < F_; ++f){
        float v = x[f];
        e[NCIN+f-1] = v;
        u16 h = f2h(v);
        eh[NCIN+f-1] = h;
        el[NCIN+f-1] = f2h(v - h2f(h));
    }
    #pragma unroll
    for (int c = ENCD; c < 32; ++c){ eh[c] = 0; el[c] = 0; }
}

// ---------------------------------------------------------------- weight prep (transpose + f16 / f16-lo)
#define NPREP 14
struct PrepArgs {
    const float* src[NPREP];
    u16* dst[NPREP];
    int K[NPREP];
    int Ka[NPREP];
    int lo[NPREP];
    int blk_end[NPREP];
};
__global__ void k_prep(PrepArgs a){
    int blk = blockIdx.x;
    int s = 0;
    while (blk >= a.blk_end[s]) s++;
    int base = s ? a.blk_end[s-1] : 0;
    int idx = (blk - base)*256 + threadIdx.x;
    int Ka = a.Ka[s];
    int n = idx / Ka, k = idx % Ka;
    float v = (k < a.K[s]) ? a.src[s][(size_t)k*H_ + n] : 0.f;
    u16 h = f2h(v);
    a.dst[s][idx] = a.lo[s] ? f2h(v - h2f(h)) : h;
}

// R [256][100] -> Rt [5][256]
__global__ void k_prepR(const float* __restrict__ R, float* __restrict__ Rt){
    int idx = blockIdx.x*256 + threadIdx.x;   // 5 blocks
    int j = idx >> 8, k = idx & 255;
    Rt[j*H_ + k] = R[(size_t)k*100 + j];
}

// ---------------------------------------------------------------- split-f16 MFMA GEMM for ffn chain
template<int ACT, int OUT>
__global__ __launch_bounds__(256) void k_ffn(const u16* __restrict__ Ahg,
        const u16* __restrict__ Alg, const u16* __restrict__ Whg,
        const u16* __restrict__ Wlg, const float* __restrict__ bias,
        float* __restrict__ Cf, u16* __restrict__ Ch, u16* __restrict__ Cl,
        int M, int K, int Nw){
    __shared__ u16 smem[12288];
    #define AH_(ks,m) (smem +        ((ks)*512  + (m)*8))
    #define AL_(ks,m) (smem + 2048 + ((ks)*512  + (m)*8))
    #define WH_(ks,m) (smem + 4096 + ((ks)*1024 + (m)*8))
    #define WL_(ks,m) (smem + 8192 + ((ks)*1024 + (m)*8))
    int tid = threadIdx.x, lane = tid & 63, w = tid >> 6;
    int wr = (w & 1)*32, wc = (w >> 1)*64;
    int m0 = blockIdx.x*64, n0 = blockIdx.y*128;
    int arow = tid >> 2, aks = tid & 3;
    const u16* ArH = Ahg + (size_t)(m0+arow)*K + aks*8;
    const u16* ArL = Alg + (size_t)(m0+arow)*K + aks*8;
    int wrow0 = tid >> 2, wks0 = tid & 3;
    int wrow1 = (tid + 256) >> 2, wks1 = tid & 3;
    const u16* WrH0 = Whg + (size_t)(n0+wrow0)*K + wks0*8;
    const u16* WrL0 = Wlg + (size_t)(n0+wrow0)*K + wks0*8;
    const u16* WrH1 = Whg + (size_t)(n0+wrow1)*K + wks1*8;
    const u16* WrL1 = Wlg + (size_t)(n0+wrow1)*K + wks1*8;
    f32x4_ z = {0.f,0.f,0.f,0.f};
    f32x4_ acc[2][4];
    #pragma unroll
    for (int i = 0; i < 2; ++i)
        #pragma unroll
        for (int j = 0; j < 4; ++j) acc[i][j] = z;
    const int fr = lane & 15, fks = lane >> 4;
    const int nc = K >> 5;
    uint4 rah, ral, rwh0, rwl0, rwh1, rwl1;

    rah  = *(const uint4*)(ArH);
    ral  = *(const uint4*)(ArL);
    rwh0 = *(const uint4*)(WrH0);
    rwl0 = *(const uint4*)(WrL0);
    rwh1 = *(const uint4*)(WrH1);
    rwl1 = *(const uint4*)(WrL1);
    *(uint4*)AH_(aks,arow) = rah;
    *(uint4*)AL_(aks,arow) = ral;
    *(uint4*)WH_(wks0,wrow0) = rwh0;
    *(uint4*)WL_(wks0,wrow0) = rwl0;
    *(uint4*)WH_(wks1,wrow1) = rwh1;
    *(uint4*)WL_(wks1,wrow1) = rwl1;
    __syncthreads();

    for (int c = 0; c < nc; ++c){
        if (c + 1 < nc){
            int k0 = (c+1)*32;
            rah  = *(const uint4*)(ArH + k0);
            ral  = *(const uint4*)(ArL + k0);
            rwh0 = *(const uint4*)(WrH0 + k0);
            rwl0 = *(const uint4*)(WrL0 + k0);
            rwh1 = *(const uint4*)(WrH1 + k0);
            rwl1 = *(const uint4*)(WrL1 + k0);
        }
        half8 afh[2], afl[2];
        #pragma unroll
        for (int mi = 0; mi < 2; ++mi){
            afh[mi] = *reinterpret_cast<const half8*>(AH_(fks, wr + mi*16 + fr));
            afl[mi] = *reinterpret_cast<const half8*>(AL_(fks, wr + mi*16 + fr));
        }
        #pragma unroll
        for (int ni = 0; ni < 4; ++ni){
            half8 wfh = *reinterpret_cast<const half8*>(WH_(fks, wc + ni*16 + fr));
            half8 wfl = *reinterpret_cast<const half8*>(WL_(fks, wc + ni*16 + fr));
            #pragma unroll
            for (int mi = 0; mi < 2; ++mi){
                acc[mi][ni] = __builtin_amdgcn_mfma_f32_16x16x32_f16(afh[mi], wfh, acc[mi][ni], 0, 0, 0);
                acc[mi][ni] = __builtin_amdgcn_mfma_f32_16x16x32_f16(afh[mi], wfl, acc[mi][ni], 0, 0, 0);
                acc[mi][ni] = __builtin_amdgcn_mfma_f32_16x16x32_f16(afl[mi], wfh, acc[mi][ni], 0, 0, 0);
            }
        }
        if (c + 1 < nc){
            __syncthreads();
            *(uint4*)AH_(aks,arow) = rah;
            *(uint4*)AL_(aks,arow) = ral;
            *(uint4*)WH_(wks0,wrow0) = rwh0;
            *(uint4*)WL_(wks0,wrow0) = rwl0;
            *(uint4*)WH_(wks1,wrow1) = rwh1;
            *(uint4*)WL_(wks1,wrow1) = rwl1;
            __syncthreads();
        }
    }
    if (OUT == 0){
        #pragma unroll
        for (int ni = 0; ni < 4; ++ni){
            int col = n0 + wc + ni*16 + fr;
            float bv = bias ? bias[col] : 0.f;
            #pragma unroll
            for (int mi = 0; mi < 2; ++mi){
                #pragma unroll
                for (int r = 0; r < 4; ++r){
                    int row = m0 + wr + mi*16 + fks*4 + r;
                    float v = acc[mi][ni][r] + bv;
                    if (ACT == 1) v = elu_f(v);
                    Cf[(size_t)row*Nw + col] = v;
                }
            }
        }
    } else {
        __syncthreads();
        #pragma unroll
        for (int ni = 0; ni < 4; ++ni){
            int lc = wc + ni*16 + fr;
            float bv = bias ? bias[n0 + lc] : 0.f;
            #pragma unroll
            for (int mi = 0; mi < 2; ++mi)
                #pragma unroll
                for (int r = 0; r < 4; ++r){
                    int lrow = wr + mi*16 + fks*4 + r;
                    float v = acc[mi][ni][r] + bv;
                    if (ACT == 1) v = elu_f(v);
                    smem[lrow*128 + lc] = f2h(v);
                }
        }
        __syncthreads();
        int colb = (lane & 15)*8;
        #pragma unroll
        for (int it = 0; it < 4; ++it){
            int lrow = w*16 + it*4 + (lane >> 4);
            *(uint4*)&Ch[(size_t)(m0+lrow)*Nw + n0 + colb] = *(uint4*)&smem[lrow*128 + colb];
        }
        __syncthreads();
        #pragma unroll
        for (int ni = 0; ni < 4; ++ni){
            int lc = wc + ni*16 + fr;
            float bv = bias ? bias[n0 + lc] : 0.f;
            #pragma unroll
            for (int mi = 0; mi < 2; ++mi)
                #pragma unroll
                for (int r = 0; r < 4; ++r){
                    int lrow = wr + mi*16 + fks*4 + r;
                    float v = acc[mi][ni][r] + bv;
                    if (ACT == 1) v = elu_f(v);
                    u16 h = f2h(v);
                    smem[lrow*128 + lc] = f2h(v - h2f(h));
                }
        }
        __syncthreads();
        #pragma unroll
        for (int it = 0; it < 4; ++it){
            int lrow = w*16 + it*4 + (lane >> 4);
            *(uint4*)&Cl[(size_t)(m0+lrow)*Nw + n0 + colb] = *(uint4*)&smem[lrow*128 + colb];
        }
    }
    #undef AH_
    #undef AL_
    #undef WH_
    #undef WL_
}

// ---------------------------------------------------------------- f16 MFMA GEMM, double-buffered,
// LDS-staged coalesced u16 epilogue. 1D grid with bijective XCD-chunked swizzle (626 = 8*78 + 2).
template<int ACT>
__global__ __launch_bounds__(256) void k_gemm_f16(const u16* __restrict__ A,
        const u16* __restrict__ Wt, const float* __restrict__ bias,
        float* __restrict__ Cf, u16* __restrict__ Cb, int M, int K, int Nw){
    __shared__ u16 smem[16384];
    #define ALS_(cb,ks,m) (smem +        ((cb)*4096 + (ks)*1024 + (m)*8))
    #define BLS_(cb,ks,m) (smem + 8192 + ((cb)*4096 + (ks)*1024 + (m)*8))
    int tid = threadIdx.x;
    int lane = tid & 63, w = tid >> 6;
    int wr = (w >> 1)*64, wc = (w & 1)*64;
    int lin = blockIdx.x;
    int xcd = lin & 7, jj = lin >> 3;
    int wk = (xcd < 2 ? xcd*79 : 2*79 + (xcd-2)*78) + jj;
    int m0 = (wk >> 1)*128, n0 = (wk & 1)*128;
    int mloc = tid & 127;
    int ksl  = tid >> 7;
    int gmA = m0 + mloc; if (gmA >= M) gmA = M - 1;
    const u16* Arow = A  + (size_t)gmA*K;
    const u16* Brow = Wt + (size_t)(n0 + mloc)*K;
    f32x4_ z = {0.f, 0.f, 0.f, 0.f};
    f32x4_ acc[4][4];
    #pragma unroll
    for (int i = 0; i < 4; ++i)
        #pragma unroll
        for (int j = 0; j < 4; ++j) acc[i][j] = z;
    const int fr = lane & 15, fks = lane >> 4;
    int nc = K >> 5;
    uint4 sa0, sa1, sb0, sb1;

    sa0 = *(const uint4*)(Arow + ksl*8);
    sa1 = *(const uint4*)(Arow + 16 + ksl*8);
    sb0 = *(const uint4*)(Brow + ksl*8);
    sb1 = *(const uint4*)(Brow + 16 + ksl*8);
    *(uint4*)ALS_(0,ksl,  mloc) = sa0;
    *(uint4*)ALS_(0,ksl+2,mloc) = sa1;
    *(uint4*)BLS_(0,ksl,  mloc) = sb0;
    *(uint4*)BLS_(0,ksl+2,mloc) = sb1;
    __syncthreads();

    for (int c = 0; c < nc; ++c){
        if (c + 1 < nc){
            int k0 = (c+1)*32;
            sa0 = *(const uint4*)(Arow + k0 + ksl*8);
            sa1 = *(const uint4*)(Arow + k0 + 16 + ksl*8);
            sb0 = *(const uint4*)(Brow + k0 + ksl*8);
            sb1 = *(const uint4*)(Brow + k0 + 16 + ksl*8);
        }
        int cb = c & 1;
        half8 af[4], bf[4];
        #pragma unroll
        for (int mi = 0; mi < 4; ++mi)
            af[mi] = *reinterpret_cast<const half8*>(ALS_(cb, fks, wr + mi*16 + fr));
        #pragma unroll
        for (int ni = 0; ni < 4; ++ni)
            bf[ni] = *reinterpret_cast<const half8*>(BLS_(cb, fks, wc + ni*16 + fr));
        #pragma unroll
        for (int mi = 0; mi < 4; ++mi)
            #pragma unroll
            for (int ni = 0; ni < 4; ++ni)
                acc[mi][ni] = __builtin_amdgcn_mfma_f32_16x16x32_f16(af[mi], bf[ni], acc[mi][ni], 0, 0, 0);
        if (c + 1 < nc){
            __syncthreads();
            int nb2 = (c+1) & 1;
            *(uint4*)ALS_(nb2,ksl,  mloc) = sa0;
            *(uint4*)ALS_(nb2,ksl+2,mloc) = sa1;
            *(uint4*)BLS_(nb2,ksl,  mloc) = sb0;
            *(uint4*)BLS_(nb2,ksl+2,mloc) = sb1;
            __syncthreads();
        }
    }
    if (Cb){
        __syncthreads();
        #pragma unroll
        for (int ni = 0; ni < 4; ++ni){
            int lc = wc + ni*16 + fr;
            float bv = bias ? bias[n0 + lc] : 0.f;
            #pragma unroll
            for (int mi = 0; mi < 4; ++mi)
                #pragma unroll
                for (int r = 0; r < 4; ++r){
                    int lrow = wr + mi*16 + fks*4 + r;
                    float v = acc[mi][ni][r] + bv;
                    if (ACT == 2) v = selu_f(v);
                    else if (ACT == 3) v = sigmoid_f(v);
                    smem[lrow*128 + lc] = f2h(v);
                }
        }
        __syncthreads();
        int colb = (lane & 15)*8;
        #pragma unroll
        for (int it = 0; it < 8; ++it){
            int lrow = w*32 + it*4 + (lane >> 4);
            int grow = m0 + lrow;
            if (grow < M)
                *(uint4*)&Cb[(size_t)grow*Nw + n0 + colb] = *(uint4*)&smem[lrow*128 + colb];
        }
    } else {
        #pragma unroll
        for (int ni = 0; ni < 4; ++ni){
            int col = n0 + wc + ni*16 + fr;
            float bv = bias ? bias[col] : 0.f;
            #pragma unroll
            for (int mi = 0; mi < 4; ++mi)
                #pragma unroll
                for (int r = 0; r < 4; ++r){
                    int row = m0 + wr + mi*16 + fks*4 + r;
                    if (row < M){
                        float v = acc[mi][ni][r] + bv;
                        if (ACT == 2) v = selu_f(v);
                        else if (ACT == 3) v = sigmoid_f(v);
                        Cf[(size_t)row*Nw + col] = v;
                    }
                }
        }
    }
    #undef ALS_
    #undef BLS_
}

// ---------------------------------------------------------------- fused gate/het/hom f16 MFMA GEMM,
// LDS-staged coalesced u16 epilogue. 1D grid with bijective XCD-chunked swizzle (1878 = 8*234 + 6).
__global__ __launch_bounds__(256) void k_gemm_f16x3(const u16* __restrict__ A,
        const u16* __restrict__ Wtcat, const float* __restrict__ bt,
        u16* __restrict__ G, u16* __restrict__ Hh, u16* __restrict__ Hm, int M){
    const int K = H_;
    __shared__ u16 smem[16384];
    #define ALS_(cb,ks,m) (smem +        ((cb)*4096 + (ks)*1024 + (m)*8))
    #define BLS_(cb,ks,m) (smem + 8192 + ((cb)*4096 + (ks)*1024 + (m)*8))
    int tid = threadIdx.x;
    int lane = tid & 63, w = tid >> 6;
    int wr = (w >> 1)*64, wc = (w & 1)*64;
    int lin = blockIdx.x;
    int xcd = lin & 7, jj = lin >> 3;
    int wk = (xcd < 6 ? xcd*235 : 6*235 + (xcd-6)*234) + jj;
    int m0 = (wk/6)*128;
    int yy = wk % 6;
    int seg = yy >> 1;
    u16* Cb = seg == 0 ? G : (seg == 1 ? Hh : Hm);
    int c0 = (yy & 1)*128;
    int n0 = yy*128;
    int mloc = tid & 127;
    int ksl  = tid >> 7;
    int gmA = m0 + mloc; if (gmA >= M) gmA = M - 1;
    const u16* Arow = A     + (size_t)gmA*K;
    const u16* Brow = Wtcat + (size_t)(n0 + mloc)*K;
    f32x4_ z = {0.f, 0.f, 0.f, 0.f};
    f32x4_ acc[4][4];
    #pragma unroll
    for (int i = 0; i < 4; ++i)
        #pragma unroll
        for (int j = 0; j < 4; ++j) acc[i][j] = z;
    const int fr = lane & 15, fks = lane >> 4;
    const int nc = K >> 5;
    uint4 sa0, sa1, sb0, sb1;
    sa0 = *(const uint4*)(Arow + ksl*8);
    sa1 = *(const uint4*)(Arow + 16 + ksl*8);
    sb0 = *(const uint4*)(Brow + ksl*8);
    sb1 = *(const uint4*)(Brow + 16 + ksl*8);
    *(uint4*)ALS_(0,ksl,  mloc) = sa0;
    *(uint4*)ALS_(0,ksl+2,mloc) = sa1;
    *(uint4*)BLS_(0,ksl,  mloc) = sb0;
    *(uint4*)BLS_(0,ksl+2,mloc) = sb1;
    __syncthreads();
    for (int c = 0; c < nc; ++c){
        if (c + 1 < nc){
            int k0 = (c+1)*32;
            sa0 = *(const uint4*)(Arow + k0 + ksl*8);
            sa1 = *(const uint4*)(Arow + k0 + 16 + ksl*8);
            sb0 = *(const uint4*)(Brow + k0 + ksl*8);
            sb1 = *(const uint4*)(Brow + k0 + 16 + ksl*8);
        }
        int cb = c & 1;
        half8 af[4], bf[4];
        #pragma unroll
        for (int mi = 0; mi < 4; ++mi)
            af[mi] = *reinterpret_cast<const half8*>(ALS_(cb, fks, wr + mi*16 + fr));
        #pragma unroll
        for (int ni = 0; ni < 4; ++ni)
            bf[ni] = *reinterpret_cast<const half8*>(BLS_(cb, fks, wc + ni*16 + fr));
        #pragma unroll
        for (int mi = 0; mi < 4; ++mi)
            #pragma unroll
            for (int ni = 0; ni < 4; ++ni)
                acc[mi][ni] = __builtin_amdgcn_mfma_f32_16x16x32_f16(af[mi], bf[ni], acc[mi][ni], 0, 0, 0);
        if (c + 1 < nc){
            __syncthreads();
            int nb2 = (c+1) & 1;
            *(uint4*)ALS_(nb2,ksl,  mloc) = sa0;
            *(uint4*)ALS_(nb2,ksl+2,mloc) = sa1;
            *(uint4*)BLS_(nb2,ksl,  mloc) = sb0;
            *(uint4*)BLS_(nb2,ksl+2,mloc) = sb1;
            __syncthreads();
        }
    }
    __syncthreads();
    #pragma unroll
    for (int ni = 0; ni < 4; ++ni){
        int lc = wc + ni*16 + fr;
        float bv = (seg == 0 && bt) ? bt[c0 + lc] : 0.f;
        #pragma unroll
        for (int mi = 0; mi < 4; ++mi)
            #pragma unroll
            for (int r = 0; r < 4; ++r){
                int lrow = wr + mi*16 + fks*4 + r;
                float v = acc[mi][ni][r] + bv;
                if (seg == 0) v = sigmoid_f(v);
                smem[lrow*128 + lc] = f2h(v);
            }
    }
    __syncthreads();
    int colb = (lane & 15)*8;
    #pragma unroll
    for (int it = 0; it < 8; ++it){
        int lrow = w*32 + it*4 + (lane >> 4);
        int grow = m0 + lrow;
        if (grow < M)
            *(uint4*)&Cb[(size_t)grow*H_ + c0 + colb] = *(uint4*)&smem[lrow*128 + colb];
    }
    #undef ALS_
    #undef BLS_
}

// ---------------------------------------------------------------- small-N GEMM (f16 A, fp32 W), Nw=8 or 3
__global__ void k_gemm_small(const u16* __restrict__ A, const float* __restrict__ W,
        const float* __restrict__ bias, float* __restrict__ C, int M, int K, int Nw){
    int t = blockIdx.x*blockDim.x + threadIdx.x;
    if (t >= M*Nw) return;
    int m = t / Nw, c = t % Nw;
    const u16* a = A + (size_t)m*K;
    float acc = 0.f;
    for (int k = 0; k < K; k += 8){
        uint4 u = *(const uint4*)(a + k);
        const u16* us = (const u16*)&u;
        #pragma unroll
        for (int j = 0; j < 8; ++j) acc += h2f(us[j]) * W[(k+j)*Nw + c];
    }
    C[t] = acc + bias[c];
}

// ---------------------------------------------------------------- LSH bin assignment: one wave per row
__global__ __launch_bounds__(256) void k_bins(const float* __restrict__ xd,
        const float* __restrict__ Rt, int* __restrict__ bin_idx){
    int g = blockIdx.x*4 + (threadIdx.x >> 6);
    int lane = threadIdx.x & 63;
    const float4* p = (const float4*)(xd + (size_t)g*H_);
    float4 x = p[lane];
    float acc[5];
    #pragma unroll
    for (int j = 0; j < 5; ++j){
        float4 r = ((const float4*)(Rt + j*H_))[lane];
        acc[j] = x.x*r.x + x.y*r.y + x.z*r.z + x.w*r.w;
    }
    #pragma unroll
    for (int off = 32; off; off >>= 1)
        #pragma unroll
        for (int j = 0; j < 5; ++j) acc[j] += __shfl_xor(acc[j], off, 64);
    if (lane == 0){
        float best = acc[0]; int bi = 0;
        #pragma unroll
        for (int j = 1; j < 5; ++j) if (acc[j] > best){ best = acc[j]; bi = j; }
        #pragma unroll
        for (int j = 0; j < 5; ++j){ float v = -acc[j]; if (v > best){ best = v; bi = 5 + j; } }
        bin_idx[g] = bi;
    }
}

// ---------------------------------------------------------------- stable counting sort (per batch)
__global__ __launch_bounds__(256) void k_sort(const int* __restrict__ bin_idx,
                                              int* __restrict__ order){
    int b = blockIdx.x;
    const int* bi = bin_idx + b*N_;
    int* ord = order + b*N_;
    __shared__ int cnt[256][NBINS];
    __shared__ int binoff[NBINS];
    int t = threadIdx.x;
    const int CH = (N_ + 255)/256;  // 20
    int lo = t*CH, hi = lo+CH < N_ ? lo+CH : N_;
    for (int j = 0; j < NBINS; ++j) cnt[t][j] = 0;
    for (int n = lo; n < hi; ++n) cnt[t][bi[n]]++;
    __syncthreads();
    if (t < NBINS){
        int run = 0;
        for (int q = 0; q < 256; ++q){ int v = cnt[q][t]; cnt[q][t] = run; run += v; }
        binoff[t] = run;
    }
    __syncthreads();
    if (t == 0){
        int run = 0;
        for (int j = 0; j < NBINS; ++j){ int v = binoff[j]; binoff[j] = run; run += v; }
    }
    __syncthreads();
    for (int n = lo; n < hi; ++n){
        int v = bi[n];
        int pos = binoff[v] + cnt[t][v]++;
        ord[pos] = n;
    }
}

// ---------------------------------------------------------------- gather points into bin order,
// split into f16 hi/lo (Markidis), plus fp32 squared norm
__global__ __launch_bounds__(256) void k_gather(const float* __restrict__ xd,
        const int* __restrict__ order, u16* __restrict__ xh, u16* __restrict__ xl,
        float* __restrict__ sqg){
    int g = blockIdx.x*4 + (threadIdx.x >> 6);
    int lane = threadIdx.x & 63;
    int b = g / N_;
    int node = order[g];
    const float4* src = (const float4*)(xd + ((size_t)b*N_ + node)*H_);
    float4 v = src[lane];
    unsigned hw0, hw1, lw0, lw1;
    {
        u16 h0 = f2h(v.x), h1 = f2h(v.y), h2 = f2h(v.z), h3 = f2h(v.w);
        u16 l0 = f2h(v.x - h2f(h0)), l1 = f2h(v.y - h2f(h1));
        u16 l2 = f2h(v.z - h2f(h2)), l3 = f2h(v.w - h2f(h3));
        hw0 = (unsigned)h0 | ((unsigned)h1 << 16);
        hw1 = (unsigned)h2 | ((unsigned)h3 << 16);
        lw0 = (unsigned)l0 | ((unsigned)l1 << 16);
        lw1 = (unsigned)l2 | ((unsigned)l3 << 16);
    }
    uint2 hw = {hw0, hw1}, lw = {lw0, lw1};
    *(uint2*)(xh + (size_t)g*H_ + lane*4) = hw;
    *(uint2*)(xl + (size_t)g*H_ + lane*4) = lw;
    float s = v.x*v.x + v.y*v.y + v.z*v.z + v.w*v.w;
    #pragma unroll
    for (int off = 32; off; off >>= 1) s += __shfl_xor(s, off, 64);
    if (lane == 0) sqg[g] = s;
}

// ---------------------------------------------------------------- distance-matrix via split-f16 MFMA
// dot = hi.hi + hi.lo + lo.hi (fp32 accum); writes RAW d2 (exp applied in k_sel).
// r17 structure (sqr/sqc in LDS, register prefetch) + XCD-chunked 1D grid
// (1280 = 8*160 exact): 16 tiles of each binlin land on the SAME XCD -> bin panel L2-hit.
// Note: binlin = xcd*10 + j/16 -> batch b's dm is written entirely by XCD b, bins ascending.
// (r24 lesson: do NOT force 5 blocks/CU via launch_bounds — live regs ~130 > 102, spills 5x.)
__global__ __launch_bounds__(256) void k_dist(const u16* __restrict__ xh,
        const u16* __restrict__ xl, const float* __restrict__ sqg,
        float* __restrict__ dm){
    int lin = blockIdx.x;
    int wk = (lin & 7)*160 + (lin >> 3);   // chunked XCD transform (1280/8 = 160)
    int binlin = wk >> 4;
    int tile = wk & 15;
    int tr = (tile >> 2)*128, tc = (tile & 3)*128;
    const u16* xhb = xh + (size_t)binlin*BINSZ*H_;
    const u16* xlb = xl + (size_t)binlin*BINSZ*H_;
    const float* sqb = sqg + binlin*BINSZ;
    __shared__ u16 Ah[4][128][8], Al[4][128][8];
    __shared__ u16 Bh[4][128][8], Bl[4][128][8];
    __shared__ float sqr[128], sqc[128];
    int tid = threadIdx.x;
    if (tid < 128){ int r = tr + tid; sqr[tid] = sqb[r < BINSZ ? r : BINSZ-1]; }
    else { int c = tc + (tid-128); sqc[tid-128] = sqb[c < BINSZ ? c : BINSZ-1]; }
    int lane = tid & 63, w = tid >> 6;
    int wr = (w >> 1)*64, wc = (w & 1)*64;
    int mloc = tid & 127, ksl = tid >> 7;
    int rA = tr + mloc; if (rA >= BINSZ) rA = BINSZ-1;
    int rC = tc + mloc; if (rC >= BINSZ) rC = BINSZ-1;
    const u16* ArH = xhb + (size_t)rA*H_ + ksl*8;
    const u16* ArL = xlb + (size_t)rA*H_ + ksl*8;
    const u16* BrH = xhb + (size_t)rC*H_ + ksl*8;
    const u16* BrL = xlb + (size_t)rC*H_ + ksl*8;
    f32x4_ z = {0.f, 0.f, 0.f, 0.f};
    f32x4_ acc[4][4];
    #pragma unroll
    for (int i = 0; i < 4; ++i)
        #pragma unroll
        for (int j = 0; j < 4; ++j) acc[i][j] = z;
    const int fr = lane & 15, fks = lane >> 4;
    uint4 pah0, pah1, pal0, pal1, pbh0, pbh1, pbl0, pbl1;

    pah0 = *(const uint4*)(ArH);      pah1 = *(const uint4*)(ArH + 16);
    pal0 = *(const uint4*)(ArL);      pal1 = *(const uint4*)(ArL + 16);
    pbh0 = *(const uint4*)(BrH);      pbh1 = *(const uint4*)(BrH + 16);
    pbl0 = *(const uint4*)(BrL);      pbl1 = *(const uint4*)(BrL + 16);
    *(uint4*)(&Ah[ksl  ][mloc][0]) = pah0;
    *(uint4*)(&Ah[ksl+2][mloc][0]) = pah1;
    *(uint4*)(&Al[ksl  ][mloc][0]) = pal0;
    *(uint4*)(&Al[ksl+2][mloc][0]) = pal1;
    *(uint4*)(&Bh[ksl  ][mloc][0]) = pbh0;
    *(uint4*)(&Bh[ksl+2][mloc][0]) = pbh1;
    *(uint4*)(&Bl[ksl  ][mloc][0]) = pbl0;
    *(uint4*)(&Bl[ksl+2][mloc][0]) = pbl1;
    __syncthreads();

    const int NCH = H_/32;   // 8
    for (int cc = 0; cc < NCH; ++cc){
        if (cc + 1 < NCH){
            int k0 = (cc+1)*32;
            pah0 = *(const uint4*)(ArH + k0);      pah1 = *(const uint4*)(ArH + k0 + 16);
            pal0 = *(const uint4*)(ArL + k0);      pal1 = *(const uint4*)(ArL + k0 + 16);
            pbh0 = *(const uint4*)(BrH + k0);      pbh1 = *(const uint4*)(BrH + k0 + 16);
            pbl0 = *(const uint4*)(BrL + k0);      pbl1 = *(const uint4*)(BrL + k0 + 16);
        }
        half8 afh[4], afl[4];
        #pragma unroll
        for (int mi = 0; mi < 4; ++mi){
            afh[mi] = *reinterpret_cast<const half8*>(&Ah[fks][wr + mi*16 + fr][0]);
            afl[mi] = *reinterpret_cast<const half8*>(&Al[fks][wr + mi*16 + fr][0]);
        }
        #pragma unroll
        for (int ni = 0; ni < 4; ++ni){
            half8 bfh = *reinterpret_cast<const half8*>(&Bh[fks][wc + ni*16 + fr][0]);
            half8 bfl = *reinterpret_cast<const half8*>(&Bl[fks][wc + ni*16 + fr][0]);
            #pragma unroll
            for (int mi = 0; mi < 4; ++mi){
                acc[mi][ni] = __builtin_amdgcn_mfma_f32_16x16x32_f16(afh[mi], bfh, acc[mi][ni], 0, 0, 0);
                acc[mi][ni] = __builtin_amdgcn_mfma_f32_16x16x32_f16(afh[mi], bfl, acc[mi][ni], 0, 0, 0);
                acc[mi][ni] = __builtin_amdgcn_mfma_f32_16x16x32_f16(afl[mi], bfh, acc[mi][ni], 0, 0, 0);
            }
        }
        if (cc + 1 < NCH){
            __syncthreads();
            *(uint4*)(&Ah[ksl  ][mloc][0]) = pah0;
            *(uint4*)(&Ah[ksl+2][mloc][0]) = pah1;
            *(uint4*)(&Al[ksl  ][mloc][0]) = pal0;
            *(uint4*)(&Al[ksl+2][mloc][0]) = pal1;
            *(uint4*)(&Bh[ksl  ][mloc][0]) = pbh0;
            *(uint4*)(&Bh[ksl+2][mloc][0]) = pbh1;
            *(uint4*)(&Bl[ksl  ][mloc][0]) = pbl0;
            *(uint4*)(&Bl[ksl+2][mloc][0]) = pbl1;
            __syncthreads();
        }
    }
    #pragma unroll
    for (int mi = 0; mi < 4; ++mi){
        #pragma unroll
        for (int r = 0; r < 4; ++r){
            int lr = wr + mi*16 + fks*4 + r;
            int rg = tr + lr;
            if (rg >= BINSZ) continue;
            float sr = sqr[lr];
            #pragma unroll
            for (int ni = 0; ni < 4; ++ni){
                int lc = wc + ni*16 + fr;
                int c = tc + lc;
                if (c >= BINSZ) continue;
                float d2 = sr - 2.f*acc[mi][ni][r] + sqc[lc];
                dm[((size_t)binlin*BINSZ + rg)*BINSZ + c] = d2;
            }
        }
    }
}

// ---------------------------------------------------------------- top-16 selection, TWO rows per wave
// (32 lanes/row). 16 candidates/lane in NAMED u64 regs (d2_bits<<32)|idx, bitonic-sorted
// ascending; per round ONE 5-step u64 shfl-min + shift-extract. u64-min == reference tie-break.
// Block swizzle: batch = lin&7, reverse bin order.
__global__ __launch_bounds__(256) void k_sel(const float* __restrict__ dmraw,
        const int* __restrict__ order,
        int* __restrict__ nbr_idx, float* __restrict__ nbr_val,
        float* __restrict__ nrm){
    int lin = blockIdx.x;
    int bb = lin & 7;
    int jj = lin >> 3;                     // 0..624
    int lane = threadIdx.x & 63;
    int half = lane >> 5;
    int l32  = lane & 31;
    int g = bb*N_ + (N_ - 8 - jj*8) + (threadIdx.x >> 6)*2 + half;
    int b = g / N_, pos = g % N_;
    int bin = pos / BINSZ, r = pos % BINSZ;
    int binlin = b*NBINS + bin;
    const float* row = dmraw + ((size_t)binlin*BINSZ + r)*BINSZ;

    typedef unsigned long long u64;
    #define LOADK(i) u64 k##i; { int c = l32 + (i)*32; \
        if (c < BINSZ){ unsigned db = __float_as_uint(fmaxf(row[c], 1e-6f)); \
            k##i = ((u64)db << 32) | (unsigned)c; } else k##i = ~0ull; }
    LOADK(0) LOADK(1) LOADK(2)  LOADK(3)  LOADK(4)  LOADK(5)  LOADK(6)  LOADK(7)
    LOADK(8) LOADK(9) LOADK(10) LOADK(11) LOADK(12) LOADK(13) LOADK(14) LOADK(15)
    #undef LOADK

    #define CSU(a,b) { u64 mn_ = a < b ? a : b; u64 mx_ = a < b ? b : a; a = mn_; b = mx_; }
    #define CSD(a,b) { u64 mn_ = a < b ? a : b; u64 mx_ = a < b ? b : a; a = mx_; b = mn_; }
    CSU(k0,k1) CSD(k2,k3) CSU(k4,k5) CSD(k6,k7) CSU(k8,k9) CSD(k10,k11) CSU(k12,k13) CSD(k14,k15)
    CSU(k0,k2) CSU(k1,k3) CSD(k4,k6) CSD(k5,k7) CSU(k8,k10) CSU(k9,k11) CSD(k12,k14) CSD(k13,k15)
    CSU(k0,k1) CSU(k2,k3) CSD(k4,k5) CSD(k6,k7) CSU(k8,k9) CSU(k10,k11) CSD(k12,k13) CSD(k14,k15)
    CSU(k0,k4) CSU(k1,k5) CSU(k2,k6) CSU(k3,k7) CSD(k8,k12) CSD(k9,k13) CSD(k10,k14) CSD(k11,k15)
    CSU(k0,k2) CSU(k1,k3) CSU(k4,k6) CSU(k5,k7) CSD(k8,k10) CSD(k9,k11) CSD(k12,k14) CSD(k13,k15)
    CSU(k0,k1) CSU(k2,k3) CSU(k4,k5) CSU(k6,k7) CSD(k8,k9) CSD(k10,k11) CSD(k12,k13) CSD(k14,k15)
    CSU(k0,k8) CSU(k1,k9) CSU(k2,k10) CSU(k3,k11) CSU(k4,k12) CSU(k5,k13) CSU(k6,k14) CSU(k7,k15)
    CSU(k0,k4) CSU(k1,k5) CSU(k2,k6)  CSU(k3,k7)  CSU(k8,k12) CSU(k9,k13) CSU(k10,k14) CSU(k11,k15)
    CSU(k0,k2) CSU(k1,k3) CSU(k4,k6)  CSU(k5,k7)  CSU(k8,k10) CSU(k9,k11) CSU(k12,k14) CSU(k13,k15)
    CSU(k0,k1) CSU(k2,k3) CSU(k4,k5)  CSU(k6,k7)  CSU(k8,k9)  CSU(k10,k11) CSU(k12,k13) CSU(k14,k15)
    #undef CSU
    #undef CSD

    u64 mykey = ~0ull;
    #pragma unroll
    for (int rr = 0; rr < KNN; ++rr){
        u64 m = k0;
        #pragma unroll
        for (int off = 16; off; off >>= 1){
            u64 o = __shfl_xor(m, off, 64);
            if (o < m) m = o;
        }
        if (l32 == rr) mykey = m;
        bool win = (k0 == m);
        k0  = win ? k1  : k0;
        k1  = win ? k2  : k1;
        k2  = win ? k3  : k2;
        k3  = win ? k4  : k3;
        k4  = win ? k5  : k4;
        k5  = win ? k6  : k5;
        k6  = win ? k7  : k6;
        k7  = win ? k8  : k7;
        k8  = win ? k9  : k8;
        k9  = win ? k10 : k9;
        k10 = win ? k11 : k10;
        k11 = win ? k12 : k11;
        k12 = win ? k13 : k12;
        k13 = win ? k14 : k13;
        k14 = win ? k15 : k14;
        k15 = win ? ~0ull : k15;
    }
    float myd = __uint_as_float((unsigned)(mykey >> 32));
    int myc = (int)(unsigned)(mykey & 0xFFFFFFFFull);
    float myv = (l32 < KNN) ? expf(-0.1f*sqrtf(myd)) : 0.f;
    float deg = myv;
    #pragma unroll
    for (int off = 16; off; off >>= 1) deg += __shfl_xor(deg, off, 64);
    const int* ord = order + b*N_ + bin*BINSZ;
    int node_i = ord[r];
    if (l32 < KNN){
        nbr_idx[((size_t)b*N_ + node_i)*KNN + l32] = ord[myc];
        nbr_val[((size_t)b*N_ + node_i)*KNN + l32] = myv;
    }
    if (l32 == 0) nrm[b*N_ + node_i] = 1.f/sqrtf(deg + 1e-6f);
}

// ---------------------------------------------------------------- GHConv combine (f16 in, f16 out)
// batch-per-XCD block swizzle: M_TOT = 8*5000 exactly; node = (lin&7)*5000 + (lin>>3)
// puts each batch's 2.56MB hom slice on ONE XCD's 4MB L2 -> neighbor gathers L2-hit.
__global__ __launch_bounds__(256) void k_ghconv(const u16* __restrict__ gate,
        const u16* __restrict__ het, const u16* __restrict__ hom,
        const int* __restrict__ nbr_idx, const float* __restrict__ nbr_val,
        const float* __restrict__ nrm, u16* __restrict__ out){
    int lin = blockIdx.x;
    int node = (lin & 7)*N_ + (lin >> 3);
    int b = lin & 7;
    int t = threadIdx.x;
    __shared__ int nid[KNN];
    __shared__ float nv[KNN];
    if (t < KNN){
        int d = nbr_idx[(size_t)node*KNN + t];
        nid[t] = d;
        nv[t] = nbr_val[(size_t)node*KNN + t] * nrm[b*N_ + d];
    }
    __syncthreads();
    float acc = 0.f;
    #pragma unroll
    for (int k = 0; k < KNN; ++k)
        acc += nv[k] * h2f(hom[((size_t)b*N_ + nid[k])*H_ + t]);
    float ni = nrm[node];
    float g = h2f(gate[(size_t)node*H_ + t]);
    float v = g * (ni * acc) + (1.f - g) * h2f(het[(size_t)node*H_ + t]);
    out[(size_t)node*H_ + t] = f2h(selu_f(v));
}

// ---------------------------------------------------------------- xr concat -> f16 [M][64] zero-padded
__global__ void k_xr(const float* __restrict__ enc, const float* __restrict__ logits,
                     u16* __restrict__ xr_h){
    int i = blockIdx.x*blockDim.x + threadIdx.x;
    if (i >= M_TOT) return;
    const float* e = enc + (size_t)i*ENCD;
    const float* l = logits + (size_t)i*NCOUT;
    u16* x = xr_h + (size_t)i*64;
    #pragma unroll
    for (int j = 0; j < ENCD; ++j) x[j] = f2h(e[j]);
    #pragma unroll
    for (int j = 0; j < NCOUT; ++j) x[ENCD+j] = f2h(l[j]);
    #pragma unroll
    for (int j = XRD; j < 64; ++j) x[j] = 0;
}

// ----------------------------------------------------------------
extern "C" void kernel_launch(void* const* d_in, const int* in_sizes, int n_in,
                              void* d_out, int out_size, void* d_ws, size_t ws_size,
                              hipStream_t stream){
    const float* X        = (const float*)d_in[0];
    const float* ffn1_w   = (const float*)d_in[1];
    const float* ffn1_b   = (const float*)d_in[2];
    const float* ffn2_w   = (const float*)d_in[3];
    const float* ffn2_b   = (const float*)d_in[4];
    const float* R        = (const float*)d_in[5];
    const float* enc_id_w = (const float*)d_in[6];
    const float* enc_id_b = (const float*)d_in[7];
    const float* wt_id    = (const float*)d_in[8];
    const float* bt_id    = (const float*)d_in[9];
    const float* wh_id    = (const float*)d_in[10];
    const float* theta_id = (const float*)d_in[11];
    const float* dec_id_w = (const float*)d_in[12];
    const float* dec_id_b = (const float*)d_in[13];
    const float* out_id_w = (const float*)d_in[14];
    const float* out_id_b = (const float*)d_in[15];
    const float* enc_reg_w= (const float*)d_in[16];
    const float* enc_reg_b= (const float*)d_in[17];
    const float* wt_reg   = (const float*)d_in[18];
    const float* bt_reg   = (const float*)d_in[19];
    const float* wh_reg   = (const float*)d_in[20];
    const float* theta_reg= (const float*)d_in[21];
    const float* dec_reg_w= (const float*)d_in[22];
    const float* dec_reg_b= (const float*)d_in[23];
    const float* out_reg_w= (const float*)d_in[24];
    const float* out_reg_b= (const float*)d_in[25];

    float* out_logits = (float*)d_out;
    float* out_mom    = (float*)d_out + (size_t)M_TOT*NCOUT;

    float* ws = (float*)d_ws;
    size_t o = 0;
    float* enc  = ws + o; o += (size_t)M_TOT*ENCD;
    float* bufC = ws + o; o += (size_t)M_TOT*H_;   // h1 hi/lo -> xh/xl -> gate_h+het_h
    float* bufB = ws + o; o += (size_t)M_TOT*H_;   // x_dist -> dm(part1) -> hom_h
    float* bufD = ws + o; o += (size_t)M_TOT*H_;   // dm(part2)
    float* sqg  = ws + o; o += M_TOT;
    float* nrm  = ws + o; o += M_TOT;
    float* nbrv = ws + o; o += (size_t)M_TOT*KNN;
    float* Rt   = ws + o; o += 5*H_;
    int* ibase   = (int*)(ws + o);
    o += (size_t)18*M_TOT;
    int* bin_idx = ibase;
    int* order   = ibase + M_TOT;
    int* nbr_idx = ibase + 2*M_TOT;
    u16* hbase = (u16*)(ws + o);
    size_t ho = 0;
    u16* enc_h = hbase + ho; ho += (size_t)M_TOT*32;
    u16* enc_l = hbase + ho; ho += (size_t)M_TOT*32;
    u16* xr_h  = hbase + ho; ho += (size_t)M_TOT*64;
    u16* hA_h  = hbase + ho; ho += (size_t)M_TOT*H_;
    u16* h1_h  = hbase + ho; ho += (size_t)M_TOT*H_;
    u16* wt_encid  = hbase + ho; ho += 256*32;
    u16* wt_encreg = hbase + ho; ho += 256*64;
    u16* wtcat_id  = hbase + ho; ho += (size_t)768*256;
    u16* dec_id_h  = hbase + ho; ho += (size_t)256*256;
    u16* wtcat_reg = hbase + ho; ho += (size_t)768*256;
    u16* dec_reg_h = hbase + ho; ho += (size_t)256*256;
    u16* wf1h = hbase + ho; ho += 256*32;
    u16* wf1l = hbase + ho; ho += 256*32;
    u16* wf2h = hbase + ho; ho += (size_t)256*256;
    u16* wf2l = hbase + ho; ho += (size_t)256*256;
    // aliases into dead regions
    u16* h1h = (u16*)bufC;                // ffn1 out hi [M][256], live ffn1..ffn2
    u16* h1l = h1h + (size_t)M_TOT*H_;    // ffn1 out lo
    u16* xh = (u16*)bufC;                 // gathered hi f16 [M][256], live gather..dist
    u16* xl = xh + (size_t)M_TOT*H_;      // gathered lo f16
    float* dm = bufB;                     // raw d2, 80 MB spans bufB+bufD, live dist..sel
    u16* gate_h = (u16*)bufC;             // live after sel (xh/xl dead)
    u16* het_h  = gate_h + (size_t)M_TOT*H_;
    u16* hom_h  = (u16*)bufB;             // live after sel (dm dead)

    PrepArgs pa;
    const float* srcs[NPREP] = {enc_id_w, enc_reg_w, wt_id, wh_id, theta_id, dec_id_w,
                                wt_reg, wh_reg, theta_reg, dec_reg_w,
                                ffn1_w, ffn1_w, ffn2_w, ffn2_w};
    u16* dsts[NPREP] = {wt_encid, wt_encreg, wtcat_id, wtcat_id + 65536, wtcat_id + 131072,
                        dec_id_h, wtcat_reg, wtcat_reg + 65536, wtcat_reg + 131072, dec_reg_h,
                        wf1h, wf1l, wf2h, wf2l};
    int Ks[NPREP]  = {ENCD, XRD, H_, H_, H_, H_, H_, H_, H_, H_, ENCD, ENCD, H_, H_};
    int Kas[NPREP] = {32, 64, H_, H_, H_, H_, H_, H_, H_, H_, 32, 32, H_, H_};
    int los[NPREP] = {0,0,0,0,0,0,0,0,0,0, 0,1,0,1};
    int acc_blk = 0;
    for (int i = 0; i < NPREP; ++i){
        pa.src[i] = srcs[i]; pa.dst[i] = dsts[i]; pa.K[i] = Ks[i]; pa.Ka[i] = Kas[i];
        pa.lo[i] = los[i];
        acc_blk += Kas[i];
        pa.blk_end[i] = acc_blk;
    }

    dim3 b256(256);
    int nb = (M_TOT + 255)/256;
    dim3 gf(M_TOT/64, H_/128);            // k_ffn grid (625, 2)

    k_prep<<<acc_blk, b256, 0, stream>>>(pa);
    k_prepR<<<5, b256, 0, stream>>>(R, Rt);
    k_encode<<<nb, b256, 0, stream>>>(X, enc, enc_h, enc_l);

    // ---- x_dist chain (split-f16 MFMA, fp32-equivalent accuracy)
    k_ffn<1,1><<<gf, b256, 0, stream>>>(enc_h, enc_l, wf1h, wf1l, ffn1_b,
                                        nullptr, h1h, h1l, M_TOT, 32, H_);
    k_ffn<0,0><<<gf, b256, 0, stream>>>(h1h, h1l, wf2h, wf2l, ffn2_b,
                                        bufB, nullptr, nullptr, M_TOT, H_, H_);

    // ---- graph build
    k_bins<<<M_TOT/4, b256, 0, stream>>>(bufB, Rt, bin_idx);
    k_sort<<<B_, b256, 0, stream>>>(bin_idx, order);
    k_gather<<<M_TOT/4, b256, 0, stream>>>(bufB, order, xh, xl, sqg);
    k_dist<<<1280, b256, 0, stream>>>(xh, xl, sqg, dm);
    k_sel<<<M_TOT/8, b256, 0, stream>>>(dm, order, nbr_idx, nbrv, nrm);

    // ---- id branch (f16 MFMA; 1D swizzled grids)
    k_gemm_f16<2><<<626, b256, 0, stream>>>(enc_h, wt_encid, enc_id_b, nullptr, hA_h, M_TOT, 32, H_);
    k_gemm_f16x3<<<1878, b256, 0, stream>>>(hA_h, wtcat_id, bt_id, gate_h, het_h, hom_h, M_TOT);
    k_ghconv<<<M_TOT, b256, 0, stream>>>(gate_h, het_h, hom_h, nbr_idx, nbrv, nrm, h1_h);
    k_gemm_f16<2><<<626, b256, 0, stream>>>(h1_h, dec_id_h, dec_id_b, nullptr, hA_h, M_TOT, H_, H_);
    k_gemm_small<<<(M_TOT*NCOUT + 255)/256, b256, 0, stream>>>(hA_h, out_id_w, out_id_b,
                                                               out_logits, M_TOT, H_, NCOUT);

    // ---- reg branch (f16 MFMA; 1D swizzled grids)
    k_xr<<<nb, b256, 0, stream>>>(enc, out_logits, xr_h);
    k_gemm_f16<2><<<626, b256, 0, stream>>>(xr_h, wt_encreg, enc_reg_b, nullptr, h1_h, M_TOT, 64, H_);
    k_gemm_f16x3<<<1878, b256, 0, stream>>>(h1_h, wtcat_reg, bt_reg, gate_h, het_h, hom_h, M_TOT);
    k_ghconv<<<M_TOT, b256, 0, stream>>>(gate_h, het_h, hom_h, nbr_idx, nbrv, nrm, hA_h);
    k_gemm_f16<2><<<626, b256, 0, stream>>>(hA_h, dec_reg_h, dec_reg_b, nullptr, h1_h, M_TOT, H_, H_);
    k_gemm_small<<<(M_TOT*NMOM + 255)/256, b256, 0, stream>>>(h1_h, out_reg_w, out_reg_b,
                                                              out_mom, M_TOT, H_, NMOM);

    (void)in_sizes; (void)n_in; (void)out_size; (void)ws_size;
}